// Round 3
// baseline (387.775 us; speedup 1.0000x reference)
//
#include <hip/hip_runtime.h>
#include <cmath>

typedef _Float16 h8  __attribute__((ext_vector_type(8)));
typedef _Float16 h4v __attribute__((ext_vector_type(4)));
typedef float    f4  __attribute__((ext_vector_type(4)));
typedef float    f16f __attribute__((ext_vector_type(16)));

#define NB  4096
#define NIN 4096
#define NNP 512
#define NP1 4096
#define NP2 8192
#define NH  2048

__device__ __forceinline__ void g2l(const void* g, void* l) {
  __builtin_amdgcn_global_load_lds((const __attribute__((address_space(1))) void*)g,
                                   (__attribute__((address_space(3))) void*)l, 16, 0, 0);
}

// ---------------- pack f32 -> f16 (vectorized) ----------------
__global__ __launch_bounds__(256) void k_pack_f16(const float* __restrict__ in,
                                                  _Float16* __restrict__ out, int n4) {
  int i = blockIdx.x * 256 + threadIdx.x;
  if (i >= n4) return;
  f4 v = ((const f4*)in)[i];
  h4v o;
  o[0] = (_Float16)v[0]; o[1] = (_Float16)v[1];
  o[2] = (_Float16)v[2]; o[3] = (_Float16)v[3];
  ((h4v*)out)[i] = o;
}

// ---------------- transpose pack: out[n][k] = in[k][n] * optional mask ----------------
template<bool MASK>
__global__ __launch_bounds__(256) void k_packT(const float* __restrict__ in,
                                               const int* __restrict__ comp,
                                               _Float16* __restrict__ out, int K, int N) {
  __shared__ float tile[64][65];
  const int n0 = blockIdx.x * 64, k0 = blockIdx.y * 64;
  const int tx = threadIdx.x & 63, ty = threadIdx.x >> 6;
#pragma unroll
  for (int r = 0; r < 16; ++r) {
    int kk = r * 4 + ty;
    float v = in[(long)(k0 + kk) * N + n0 + tx];
    if (MASK) v *= (float)comp[(long)(k0 + kk) * NNP + ((n0 + tx) >> 3)];
    tile[kk][tx] = v;
  }
  __syncthreads();
#pragma unroll
  for (int r = 0; r < 16; ++r) {
    int nn = r * 4 + ty;
    out[(long)(n0 + nn) * K + k0 + tx] = (_Float16)tile[tx][nn];
  }
}

// ---------------- 256x256 fp16 MFMA GEMM, 32x32x16 frags, 2-phase/K-tile ----------------
// C = A[M,K] * BT[N,K]^T. EPI=0: C(fp16) = acc + bias. EPI=1: C(fp16 partial) += ks offset.
// 8 waves (2m x 4n), per-wave 128x64. LDS 128KB: 2buf x {A[2x128][64], B[2x128][64]} fp16,
// XOR-swizzle (row&7)<<4 applied on pre-swizzled global source + on ds_read address.
// Deep pipeline: all staging 3 phases ahead of its gate; vmcnt(8) gates, never 0 in loop.
template<int EPI>
__global__ __launch_bounds__(512, 1) void k_gemm8(
    const _Float16* __restrict__ A, const _Float16* __restrict__ BT,
    const float* __restrict__ bias, _Float16* __restrict__ C,
    int M, int N, int K, int nbn, int ksplit) {
  extern __shared__ char smem[];
  // bijective XCD swizzle
  const int nwg = gridDim.x;
  const int q = nwg >> 3, r = nwg & 7;
  const int xcd = blockIdx.x & 7, idx = blockIdx.x >> 3;
  const int wg = (xcd < r ? xcd * (q + 1) : r * (q + 1) + (xcd - r) * q) + idx;
  const int tpk = nwg / ksplit;
  const int ks = wg / tpk;
  const int rem = wg - ks * tpk;
  const int bm = rem / nbn, bn = rem % nbn;
  const long m0 = (long)bm << 8, n0 = (long)bn << 8;
  const int Ks = K / ksplit;
  const int NT = Ks >> 6;

  const int tid = threadIdx.x;
  const int lane = tid & 63, w = tid >> 6;
  const int wm = w >> 2, wn = w & 3;
  const int l31 = lane & 31, l5 = lane >> 5;
  const int swz = (l31 & 7) << 4;
  const int kx = l5 * 16;
  const int arb = (wm * 64 + l31) * 128;           // A row base (bytes, within half)
  const int brb = 32768 + (wn * 32 + l31) * 128;   // B row base (bytes, within half+B-region)

  const long sKb = (long)K * 2;
  const int scb = (((tid & 7) ^ ((tid >> 3) & 7)) << 4);   // pre-swizzled source column
  const char* Ag = (const char*)A + (m0 + (tid >> 3)) * sKb + (long)ks * Ks * 2 + scb;
  const char* Bg = (const char*)BT + (n0 + (tid >> 3)) * sKb + (long)ks * Ks * 2 + scb;
  const long h64 = 64 * sKb, h128 = 128 * sKb;
  const int lw = w << 10;

#define STAGE_A(buf, hh, ktb) do { \
    const char* s_ = Ag + (hh) * h128 + (ktb); \
    char* d_ = smem + (buf) * 65536 + (hh) * 16384 + lw; \
    g2l(s_, d_); g2l(s_ + h64, d_ + 8192); } while (0)
#define STAGE_B(buf, hh, ktb) do { \
    const char* s_ = Bg + (hh) * h128 + (ktb); \
    char* d_ = smem + (buf) * 65536 + 32768 + (hh) * 16384 + lw; \
    g2l(s_, d_); g2l(s_ + h64, d_ + 8192); } while (0)
#define LDA8(buf, hh, mg, ko) \
  (*(const h8*)(smem + (buf) * 65536 + (hh) * 16384 + arb + (mg) * 4096 + ((((ko) * 32) + kx) ^ swz)))
#define LDB8(buf, qn, ko) \
  (*(const h8*)(smem + (buf) * 65536 + (qn) * 16384 + brb + ((((ko) * 32) + kx) ^ swz)))
#define BARRIER() asm volatile("s_barrier" ::: "memory")

  f16f acc[2][2][2] = {};   // [qm][mg][qn]
  h8 af[2][4], bf[2][4];

  // prologue: {A0,B0,B1,A1}(t0) then {A0,B0,B1}(t1)  (issue order = vmcnt ledger)
  STAGE_A(0, 0, 0); STAGE_B(0, 0, 0); STAGE_B(0, 1, 0);
  STAGE_A(0, 1, 0);
  STAGE_A(1, 0, 128); STAGE_B(1, 0, 128); STAGE_B(1, 1, 128);

  for (int t = 0; t < NT; ++t) {
    const int cur = t & 1, nxt = cur ^ 1;
    const bool pf = (t + 1) < NT;

    // ---- P0: qm=0. Gate publishes A0,B0,B1(t).
    if (pf) asm volatile("s_waitcnt vmcnt(8)" ::: "memory");
    else    asm volatile("s_waitcnt vmcnt(2)" ::: "memory");
    BARRIER();
#pragma unroll
    for (int ko = 0; ko < 4; ++ko) {
      af[0][ko] = LDA8(cur, 0, 0, ko);
      af[1][ko] = LDA8(cur, 0, 1, ko);
      bf[0][ko] = LDB8(cur, 0, ko);
      bf[1][ko] = LDB8(cur, 1, ko);
    }
    if (pf) STAGE_A(nxt, 1, (long)(t + 1) * 128);     // A1(t+1)
    __builtin_amdgcn_s_setprio(1);
#pragma unroll
    for (int ko = 0; ko < 4; ++ko)
#pragma unroll
      for (int mg = 0; mg < 2; ++mg)
#pragma unroll
        for (int qn = 0; qn < 2; ++qn)
          acc[0][mg][qn] = __builtin_amdgcn_mfma_f32_32x32x16_f16(af[mg][ko], bf[qn][ko], acc[0][mg][qn], 0, 0, 0);
    __builtin_amdgcn_s_setprio(0);

    // ---- P1: qm=1. Gate publishes A1(t).
    if (pf) asm volatile("s_waitcnt vmcnt(8)" ::: "memory");
    else    asm volatile("s_waitcnt vmcnt(0)" ::: "memory");
    BARRIER();
#pragma unroll
    for (int ko = 0; ko < 4; ++ko) {
      af[0][ko] = LDA8(cur, 1, 0, ko);
      af[1][ko] = LDA8(cur, 1, 1, ko);
    }
    if ((t + 2) < NT) {                                // {A0,B0,B1}(t+2)
      const long kb2 = (long)(t + 2) * 128;
      STAGE_A(cur, 0, kb2); STAGE_B(cur, 0, kb2); STAGE_B(cur, 1, kb2);
    }
    __builtin_amdgcn_s_setprio(1);
#pragma unroll
    for (int ko = 0; ko < 4; ++ko)
#pragma unroll
      for (int mg = 0; mg < 2; ++mg)
#pragma unroll
        for (int qn = 0; qn < 2; ++qn)
          acc[1][mg][qn] = __builtin_amdgcn_mfma_f32_32x32x16_f16(af[mg][ko], bf[qn][ko], acc[1][mg][qn], 0, 0, 0);
    __builtin_amdgcn_s_setprio(0);
  }

  // epilogue: 32x32 C/D layout: col = lane&31, row = (r&3) + 8*(r>>2) + 4*(lane>>5)
  _Float16* dst = (EPI == 1) ? (C + (long)ks * M * N) : C;
#pragma unroll
  for (int qm = 0; qm < 2; ++qm)
#pragma unroll
    for (int mg = 0; mg < 2; ++mg) {
      const long rbase = m0 + qm * 128 + wm * 64 + mg * 32 + l5 * 4;
#pragma unroll
      for (int qn = 0; qn < 2; ++qn) {
        const long c = n0 + qn * 128 + wn * 32 + l31;
        const float bv = (EPI == 0) ? bias[c] : 0.f;
        f16f v = acc[qm][mg][qn];
#pragma unroll
        for (int rr = 0; rr < 16; ++rr) {
          const long row = rbase + (rr & 3) + 8 * (rr >> 2);
          dst[row * N + c] = (_Float16)(v[rr] + bv);
        }
      }
    }
#undef STAGE_A
#undef STAGE_B
#undef LDA8
#undef LDB8
#undef BARRIER
}

// ---------------- block-diagonal GEMM2 ----------------
__global__ __launch_bounds__(256) void k_gemm2(const _Float16* __restrict__ out1,
                                               const float* __restrict__ fc2w,
                                               const float* __restrict__ fc2b,
                                               _Float16* __restrict__ out2) {
  const int b0 = (blockIdx.x >> 4) * 64;
  const int p  = (blockIdx.x & 15) * 32 + (threadIdx.x & 31);
  const int bsub = threadIdx.x >> 5;
  f4 bb0 = *(const f4*)&fc2b[p * 16 + 0];
  f4 bb1 = *(const f4*)&fc2b[p * 16 + 4];
  f4 bb2 = *(const f4*)&fc2b[p * 16 + 8];
  f4 bb3 = *(const f4*)&fc2b[p * 16 + 12];
  for (int r = 0; r < 8; ++r) {
    const int b = b0 + r * 8 + bsub;
    h8 qv = *(const h8*)&out1[(long)b * NP1 + p * 8];
    f4 a0 = bb0, a1 = bb1, a2 = bb2, a3 = bb3;
#pragma unroll
    for (int i = 0; i < 8; ++i) {
      const float qi = (float)qv[i];
      const f4* wr = (const f4*)&fc2w[(long)(p * 8 + i) * NP2 + p * 16];
      a0 += qi * wr[0]; a1 += qi * wr[1]; a2 += qi * wr[2]; a3 += qi * wr[3];
    }
    h8 o0, o1;
#pragma unroll
    for (int u = 0; u < 4; ++u) {
      o0[u] = (_Float16)a0[u]; o0[4 + u] = (_Float16)a1[u];
      o1[u] = (_Float16)a2[u]; o1[4 + u] = (_Float16)a3[u];
    }
    h8* dstp = (h8*)&out2[(long)b * NP2 + p * 16];
    dstp[0] = o0; dstp[1] = o1;
  }
}

// ---------------- fused splitK-reduce + bias + relu + GEMM4 + sigmoid ----------------
__global__ __launch_bounds__(256) void k_logits(const _Float16* __restrict__ part,
                                                const float* __restrict__ b1,
                                                const float* __restrict__ w2,
                                                const float* __restrict__ b2,
                                                float* __restrict__ logits,
                                                float* __restrict__ hazards) {
  const int lane = threadIdx.x & 63;
  const int b = blockIdx.x * 4 + (threadIdx.x >> 6);
  const long off2 = (long)NB * NH;
  f4 acc = {0.f, 0.f, 0.f, 0.f};
  const _Float16* p0 = part + (long)b * NH;
  const _Float16* p1 = p0 + off2;
#pragma unroll
  for (int c4 = 0; c4 < 4; ++c4) {
    const int k0 = c4 * 512 + lane * 8;
    h8 a = *(const h8*)&p0[k0];
    h8 bb = *(const h8*)&p1[k0];
    f4 bva = *(const f4*)&b1[k0];
    f4 bvb = *(const f4*)&b1[k0 + 4];
#pragma unroll
    for (int u = 0; u < 8; ++u) {
      const float bias = (u < 4) ? bva[u] : bvb[u - 4];
      const float hv = fmaxf((float)a[u] + (float)bb[u] + bias, 0.f);
      acc += hv * *(const f4*)&w2[(long)(k0 + u) * 4];
    }
  }
#pragma unroll
  for (int off = 32; off > 0; off >>= 1) {
#pragma unroll
    for (int u = 0; u < 4; ++u) acc[u] += __shfl_xor(acc[u], off, 64);
  }
  if (lane == 0) {
    f4 lg = acc + *(const f4*)b2;
    ((f4*)logits)[b] = lg;
    f4 hz;
#pragma unroll
    for (int u = 0; u < 4; ++u) hz[u] = 1.f / (1.f + expf(-lg[u]));
    ((f4*)hazards)[b] = hz;
  }
}

// ---------------- cumprod along batch + first-occurrence argmax ----------------
__global__ __launch_bounds__(256) void k_final(const float* __restrict__ logits,
                                               const float* __restrict__ hazards,
                                               float* __restrict__ S,
                                               float* __restrict__ yhat) {
  const int c = blockIdx.x;
  const int t = threadIdx.x;
  __shared__ float pl[256];
  __shared__ float mv[256];
  __shared__ int   mi[256];
  float prod = 1.f;
  float best = -1e30f; int bi = 0;
  for (int i = 0; i < 16; ++i) {
    const int b = t * 16 + i;
    prod *= (1.f - hazards[b * 4 + c]);
    const float lg = logits[b * 4 + c];
    if (lg > best) { best = lg; bi = b; }
  }
  pl[t] = prod; mv[t] = best; mi[t] = bi;
  __syncthreads();
  for (int off = 1; off < 256; off <<= 1) {
    float cur  = pl[t];
    float prev = (t >= off) ? pl[t - off] : 1.f;
    __syncthreads();
    pl[t] = cur * prev;
    __syncthreads();
  }
  float s = (t == 0) ? 1.f : pl[t - 1];
  for (int i = 0; i < 16; ++i) {
    const int b = t * 16 + i;
    s *= (1.f - hazards[b * 4 + c]);
    S[b * 4 + c] = s;
  }
  for (int off = 128; off > 0; off >>= 1) {
    if (t < off) {
      float ov = mv[t + off]; int oi = mi[t + off];
      if (ov > mv[t] || (ov == mv[t] && oi < mi[t])) { mv[t] = ov; mi[t] = oi; }
    }
    __syncthreads();
  }
  if (t == 0) yhat[c] = (float)mi[0];
}

extern "C" void kernel_launch(void* const* d_in, const int* in_sizes, int n_in,
                              void* d_out, int out_size, void* d_ws, size_t ws_size,
                              hipStream_t stream) {
  (void)in_sizes; (void)n_in; (void)out_size; (void)ws_size;
  const float* x    = (const float*)d_in[0];
  const float* fc1w = (const float*)d_in[1];
  const float* fc1b = (const float*)d_in[2];
  const float* fc2w = (const float*)d_in[3];
  const float* fc2b = (const float*)d_in[4];
  const float* w1   = (const float*)d_in[5];
  const float* b1   = (const float*)d_in[6];
  const float* w2   = (const float*)d_in[7];
  const float* b2   = (const float*)d_in[8];
  const int*   comp = (const int*)d_in[9];

  char* ws = (char*)d_ws;
  const size_t MB = 1024ull * 1024ull;
  // region plan (peak 160MB):
  //   [0,32M)    xh     -> dead after GEMM1 -> w1Th
  //   [32M,64M)  w1mT   -> dead after GEMM1 -> part (fp16 2x16MB)
  //   [64M,96M)  out1h
  //   [96M,160M) out2h
  _Float16* xh     = (_Float16*)(ws + 0);
  _Float16* w1mT   = (_Float16*)(ws + 32 * MB);
  _Float16* out1h  = (_Float16*)(ws + 64 * MB);
  _Float16* out2h  = (_Float16*)(ws + 96 * MB);
  _Float16* w1Th   = (_Float16*)(ws + 0);
  _Float16* part   = (_Float16*)(ws + 32 * MB);
  float*    logits = (float*)(ws + 64 * MB);   // out1h dead by logits time? (kept separate: use +64M)
  float*    outF   = (float*)d_out;

  hipFuncSetAttribute(reinterpret_cast<const void*>(k_gemm8<0>),
                      hipFuncAttributeMaxDynamicSharedMemorySize, 131072);
  hipFuncSetAttribute(reinterpret_cast<const void*>(k_gemm8<1>),
                      hipFuncAttributeMaxDynamicSharedMemorySize, 131072);

  // 1) pack x -> fp16
  k_pack_f16<<<(NB * NIN / 4) / 256, 256, 0, stream>>>(x, xh, NB * NIN / 4);
  // 2) pack (fc1_w * mask1)^T -> fp16 [P1][IN]
  k_packT<true><<<dim3(NP1 / 64, NIN / 64), 256, 0, stream>>>(fc1w, comp, w1mT, NIN, NP1);
  // 3) GEMM1: out1 = x @ fc1w_masked + fc1_b
  k_gemm8<0><<<(NB / 256) * (NP1 / 256), 512, 131072, stream>>>(
      xh, w1mT, fc1b, out1h, NB, NP1, NIN, NP1 / 256, 1);
  // 4) block-diagonal GEMM2 -> out2 fp16
  k_gemm2<<<(NB / 64) * (NNP / 32), 256, 0, stream>>>(out1h, fc2w, fc2b, out2h);
  // 5) pack w1^T -> fp16 [H][P2] (overlays dead xh)
  k_packT<false><<<dim3(NH / 64, NP2 / 64), 256, 0, stream>>>(w1, nullptr, w1Th, NP2, NH);
  // 6) GEMM3 split-K=2: fp16 partials = out2 @ w1 (overlays dead w1mT)
  k_gemm8<1><<<(NB / 256) * (NH / 256) * 2, 512, 131072, stream>>>(
      out2h, w1Th, nullptr, part, NB, NH, NP2, NH / 256, 2);
  // 7) fused: h = relu(p0+p1+b1); logits = h@w2+b2; hazards = sigmoid
  k_logits<<<NB / 4, 256, 0, stream>>>(part, b1, w2, b2, logits, outF);
  // 8) S and Y_hat
  k_final<<<4, 256, 0, stream>>>(logits, outF, outF + NB * 4, outF + 2 * NB * 4);
}

// Round 5
// 362.123 us; speedup vs baseline: 1.0708x; 1.0708x over previous
//
#include <hip/hip_runtime.h>
#include <cmath>

typedef _Float16 h8  __attribute__((ext_vector_type(8)));
typedef _Float16 h4v __attribute__((ext_vector_type(4)));
typedef float    f4  __attribute__((ext_vector_type(4)));

#define NB  4096
#define NIN 4096
#define NNP 512
#define NP1 4096
#define NP2 8192
#define NH  2048

__device__ __forceinline__ void g2l(const void* g, void* l) {
  __builtin_amdgcn_global_load_lds((const __attribute__((address_space(1))) void*)g,
                                   (__attribute__((address_space(3))) void*)l, 16, 0, 0);
}

// ---------------- pack f32 -> f16 (vectorized) ----------------
__global__ __launch_bounds__(256) void k_pack_f16(const float* __restrict__ in,
                                                  _Float16* __restrict__ out, int n4) {
  int i = blockIdx.x * 256 + threadIdx.x;
  if (i >= n4) return;
  f4 v = ((const f4*)in)[i];
  h4v o;
  o[0] = (_Float16)v[0]; o[1] = (_Float16)v[1];
  o[2] = (_Float16)v[2]; o[3] = (_Float16)v[3];
  ((h4v*)out)[i] = o;
}

// ---------------- transpose pack: out[n][k] = in[k][n] * optional mask ----------------
template<bool MASK>
__global__ __launch_bounds__(256) void k_packT(const float* __restrict__ in,
                                               const int* __restrict__ comp,
                                               _Float16* __restrict__ out, int K, int N) {
  __shared__ float tile[64][65];
  const int n0 = blockIdx.x * 64, k0 = blockIdx.y * 64;
  const int tx = threadIdx.x & 63, ty = threadIdx.x >> 6;
#pragma unroll
  for (int r = 0; r < 16; ++r) {
    int kk = r * 4 + ty;
    float v = in[(long)(k0 + kk) * N + n0 + tx];
    if (MASK) v *= (float)comp[(long)(k0 + kk) * NNP + ((n0 + tx) >> 3)];
    tile[kk][tx] = v;
  }
  __syncthreads();
#pragma unroll
  for (int r = 0; r < 16; ++r) {
    int nn = r * 4 + ty;
    out[(long)(n0 + nn) * K + k0 + tx] = (_Float16)tile[tx][nn];
  }
}

// ---------------- 256x256 fp16 GEMM, 16x16x32 frags, 8-phase schedule ----------------
// C = A[M,K] * BT[N,K]^T. EPI=0: C = acc + bias (fp16). EPI=1: fp16 split-K partial at ks*M*N.
// 8 waves (2m x 4n). Quadrant->half interleave: A row = mh*128 + wm*64 + m*16 + lh,
// B row = nh*128 + wn*32 + n*16 + lh  (phase reads exactly one staged 128-row half; no race).
// LDS 128KB: 2buf x {A: half0,half1 ; B: half0,half1}, each half = 2 panels [128][32]fp16
// (64B rows -> measured-0 bank conflicts for (rows=lh, col=ls*16) ds_read_b128 pattern).
// Iter = 2 K-tiles (BK=64), 8 phases, 1 half stage (2xg2l) per phase; vmcnt(6) @ P4/P8 only.
template<int EPI>
__global__ __launch_bounds__(512, 1) void k_gemm8(
    const _Float16* __restrict__ A, const _Float16* __restrict__ BT,
    const float* __restrict__ bias, _Float16* __restrict__ C,
    int M, int N, int K, int nbn, int ksplit) {
  extern __shared__ char smem[];
  // bijective XCD swizzle
  const int nwg = gridDim.x;
  const int q = nwg >> 3, r = nwg & 7;
  const int xcd = blockIdx.x & 7, idx = blockIdx.x >> 3;
  const int wg = (xcd < r ? xcd * (q + 1) : r * (q + 1) + (xcd - r) * q) + idx;
  const int tpk = nwg / ksplit;
  const int ks = wg / tpk;
  const int rem = wg - ks * tpk;
  const int bm = rem / nbn, bn = rem % nbn;
  const long m0 = (long)bm << 8, n0 = (long)bn << 8;
  const int Ks = K / ksplit;
  const int NT = Ks >> 6;              // BK=64

  const int tid = threadIdx.x;
  const int lane = tid & 63, w = tid >> 6;
  const int wm = w >> 2, wn = w & 3;
  const int lh = lane & 15, ls = lane >> 4;

  // staging: lane L of wave w supplies (row-in-half = w*16 + L>>2, 16B slot = L&3);
  // g2l #1 -> panel kq0 (cols 0-31), g2l #2 (+64B src, +8192B dst) -> panel kq1.
  const long sKb = (long)K * 2;
  const int srow = (w << 4) + (lane >> 2);
  const int scol = (lane & 3) << 4;
  const char* Ag = (const char*)A + (m0 + srow) * sKb + (long)ks * Ks * 2 + scol;
  const char* Bg = (const char*)BT + (n0 + srow) * sKb + (long)ks * Ks * 2 + scol;
  const long h128 = 128 * sKb;
  const int lw = w << 10;

  const int arow = (wm * 64 + lh) * 64 + ls * 16;          // + m_*16*64
  const int brow = 32768 + (wn * 32 + lh) * 64 + ls * 16;  // + n_*16*64

#define STAGE_A(buf, hh, kb) do { \
    const char* s_ = Ag + (hh) * h128 + (kb); \
    char* d_ = smem + (buf) * 65536 + (hh) * 16384 + lw; \
    g2l(s_, d_); g2l(s_ + 64, d_ + 8192); } while (0)
#define STAGE_B(buf, hh, kb) do { \
    const char* s_ = Bg + (hh) * h128 + (kb); \
    char* d_ = smem + (buf) * 65536 + 32768 + (hh) * 16384 + lw; \
    g2l(s_, d_); g2l(s_ + 64, d_ + 8192); } while (0)
#define RDA(buf, mh) do { \
    _Pragma("unroll") for (int m_ = 0; m_ < 4; ++m_) { \
      af[m_][0] = *(const h8*)(smem + (buf) * 65536 + (mh) * 16384 + arow + m_ * 1024); \
      af[m_][1] = *(const h8*)(smem + (buf) * 65536 + (mh) * 16384 + 8192 + arow + m_ * 1024); } } while (0)
#define RDB(buf, nh) do { \
    _Pragma("unroll") for (int n_ = 0; n_ < 2; ++n_) { \
      bf[n_][0] = *(const h8*)(smem + (buf) * 65536 + (nh) * 16384 + brow + n_ * 1024); \
      bf[n_][1] = *(const h8*)(smem + (buf) * 65536 + (nh) * 16384 + 8192 + brow + n_ * 1024); } } while (0)
#define MM(mh, nh) do { \
    _Pragma("unroll") for (int kq_ = 0; kq_ < 2; ++kq_) \
    _Pragma("unroll") for (int m_ = 0; m_ < 4; ++m_) \
    _Pragma("unroll") for (int n_ = 0; n_ < 2; ++n_) \
      acc[mh][nh][m_][n_] = __builtin_amdgcn_mfma_f32_16x16x32_f16(af[m_][kq_], bf[n_][kq_], acc[mh][nh][m_][n_], 0, 0, 0); } while (0)
#define BAR() asm volatile("s_barrier" ::: "memory")
#define LG0() asm volatile("s_waitcnt lgkmcnt(0)" ::: "memory")
#define LG8() asm volatile("s_waitcnt lgkmcnt(8)" ::: "memory")
#define VM6() asm volatile("s_waitcnt vmcnt(6)" ::: "memory")
#define PR1() __builtin_amdgcn_s_setprio(1)
#define PR0() __builtin_amdgcn_s_setprio(0)

  f4 acc[2][2][4][2] = {};   // [mh][nh][m][n]
  h8 af[4][2], bf[2][2];

  auto kc = [&](int t) -> long { return (long)(t < NT ? t : NT - 1) << 7; };

  // prologue: full tile0 (buf0) + {A0,B1,A1}(tile1, buf1); VM6 retires tile0's 4 halves
  STAGE_A(0, 0, kc(0));
  STAGE_B(0, 1, kc(0));
  STAGE_A(0, 1, kc(0));
  STAGE_B(0, 0, kc(0));
  STAGE_A(1, 0, kc(1));
  STAGE_B(1, 1, kc(1));
  STAGE_A(1, 1, kc(1));
  VM6(); BAR();

  for (int t2 = 0; t2 < NT; t2 += 2) {
    // ---------- K-tile t2 (buf0) ----------
    // P1: (mh0,nh0); stage B0(t2+1)->buf1 (slot last read at prev P8)
    RDA(0, 0); RDB(0, 0);
    STAGE_B(1, 0, kc(t2 + 1));
    LG8(); BAR(); LG0();
    PR1(); MM(0, 0); PR0(); BAR();
    // P2: (mh0,nh1); stage A0(t2+2)->buf0 (A-half0 last read at P1)
    RDB(0, 1);
    STAGE_A(0, 0, kc(t2 + 2));
    BAR(); LG0();
    PR1(); MM(0, 1); PR0(); BAR();
    // P3: (mh1,nh1); stage B1(t2+2)->buf0 (B-half1 last read at P2)
    RDA(0, 1);
    STAGE_B(0, 1, kc(t2 + 2));
    BAR(); LG0();
    PR1(); MM(1, 1); PR0(); BAR();
    // P4: (mh1,nh0) re-reads B-half0; stage A1(t2+2)->buf0 (A-half1 last read at P3)
    RDB(0, 0);
    STAGE_A(0, 1, kc(t2 + 2));
    BAR(); LG0();
    PR1(); MM(1, 0); PR0();
    VM6(); BAR();                       // tile t2+1 (buf1) fully landed
    // ---------- K-tile t2+1 (buf1) ----------
    // P5; stage B0(t2+2)->buf0 (B-half0 last read at P4)
    RDA(1, 0); RDB(1, 0);
    STAGE_B(0, 0, kc(t2 + 2));
    LG8(); BAR(); LG0();
    PR1(); MM(0, 0); PR0(); BAR();
    // P6; stage A0(t2+3)->buf1 (A-half0 last read at P5)
    RDB(1, 1);
    STAGE_A(1, 0, kc(t2 + 3));
    BAR(); LG0();
    PR1(); MM(0, 1); PR0(); BAR();
    // P7; stage B1(t2+3)->buf1 (B-half1 last read at P6)
    RDA(1, 1);
    STAGE_B(1, 1, kc(t2 + 3));
    BAR(); LG0();
    PR1(); MM(1, 1); PR0(); BAR();
    // P8; stage A1(t2+3)->buf1 (A-half1 last read at P7)
    RDB(1, 0);
    STAGE_A(1, 1, kc(t2 + 3));
    BAR(); LG0();
    PR1(); MM(1, 0); PR0();
    VM6(); BAR();                       // tile t2+2 (buf0) fully landed
  }

  // epilogue: 16x16 C/D layout col=lane&15, row=(lane>>4)*4+j
  _Float16* dst = (EPI == 1) ? (C + (long)ks * M * N) : C;
#pragma unroll
  for (int mh = 0; mh < 2; ++mh)
#pragma unroll
  for (int m = 0; m < 4; ++m) {
    const long r0 = m0 + mh * 128 + wm * 64 + m * 16 + ls * 4;
#pragma unroll
    for (int nh = 0; nh < 2; ++nh)
#pragma unroll
    for (int n = 0; n < 2; ++n) {
      const long c = n0 + nh * 128 + wn * 32 + n * 16 + lh;
      const float bv = (EPI == 0) ? bias[c] : 0.f;
#pragma unroll
      for (int j = 0; j < 4; ++j)
        dst[(r0 + j) * N + c] = (_Float16)(acc[mh][nh][m][n][j] + bv);
    }
  }
#undef STAGE_A
#undef STAGE_B
#undef RDA
#undef RDB
#undef MM
#undef BAR
#undef LG0
#undef LG8
#undef VM6
#undef PR1
#undef PR0
}

// ---------------- block-diagonal GEMM2 ----------------
__global__ __launch_bounds__(256) void k_gemm2(const _Float16* __restrict__ out1,
                                               const float* __restrict__ fc2w,
                                               const float* __restrict__ fc2b,
                                               _Float16* __restrict__ out2) {
  const int b0 = (blockIdx.x >> 4) * 64;
  const int p  = (blockIdx.x & 15) * 32 + (threadIdx.x & 31);
  const int bsub = threadIdx.x >> 5;
  f4 bb0 = *(const f4*)&fc2b[p * 16 + 0];
  f4 bb1 = *(const f4*)&fc2b[p * 16 + 4];
  f4 bb2 = *(const f4*)&fc2b[p * 16 + 8];
  f4 bb3 = *(const f4*)&fc2b[p * 16 + 12];
  for (int r = 0; r < 8; ++r) {
    const int b = b0 + r * 8 + bsub;
    h8 qv = *(const h8*)&out1[(long)b * NP1 + p * 8];
    f4 a0 = bb0, a1 = bb1, a2 = bb2, a3 = bb3;
#pragma unroll
    for (int i = 0; i < 8; ++i) {
      const float qi = (float)qv[i];
      const f4* wr = (const f4*)&fc2w[(long)(p * 8 + i) * NP2 + p * 16];
      a0 += qi * wr[0]; a1 += qi * wr[1]; a2 += qi * wr[2]; a3 += qi * wr[3];
    }
    h8 o0, o1;
#pragma unroll
    for (int u = 0; u < 4; ++u) {
      o0[u] = (_Float16)a0[u]; o0[4 + u] = (_Float16)a1[u];
      o1[u] = (_Float16)a2[u]; o1[4 + u] = (_Float16)a3[u];
    }
    h8* dstp = (h8*)&out2[(long)b * NP2 + p * 16];
    dstp[0] = o0; dstp[1] = o1;
  }
}

// ---------------- fused splitK-reduce + bias + relu + GEMM4 + sigmoid ----------------
__global__ __launch_bounds__(256) void k_logits(const _Float16* __restrict__ part,
                                                const float* __restrict__ b1,
                                                const float* __restrict__ w2,
                                                const float* __restrict__ b2,
                                                float* __restrict__ logits,
                                                float* __restrict__ hazards) {
  const int lane = threadIdx.x & 63;
  const int b = blockIdx.x * 4 + (threadIdx.x >> 6);
  const long off2 = (long)NB * NH;
  f4 acc = {0.f, 0.f, 0.f, 0.f};
  const _Float16* p0 = part + (long)b * NH;
  const _Float16* p1 = p0 + off2;
#pragma unroll
  for (int c4 = 0; c4 < 4; ++c4) {
    const int k0 = c4 * 512 + lane * 8;
    h8 a = *(const h8*)&p0[k0];
    h8 bb = *(const h8*)&p1[k0];
    f4 bva = *(const f4*)&b1[k0];
    f4 bvb = *(const f4*)&b1[k0 + 4];
#pragma unroll
    for (int u = 0; u < 8; ++u) {
      const float bias = (u < 4) ? bva[u] : bvb[u - 4];
      const float hv = fmaxf((float)a[u] + (float)bb[u] + bias, 0.f);
      acc += hv * *(const f4*)&w2[(long)(k0 + u) * 4];
    }
  }
#pragma unroll
  for (int off = 32; off > 0; off >>= 1) {
#pragma unroll
    for (int u = 0; u < 4; ++u) acc[u] += __shfl_xor(acc[u], off, 64);
  }
  if (lane == 0) {
    f4 lg = acc + *(const f4*)b2;
    ((f4*)logits)[b] = lg;
    f4 hz;
#pragma unroll
    for (int u = 0; u < 4; ++u) hz[u] = 1.f / (1.f + expf(-lg[u]));
    ((f4*)hazards)[b] = hz;
  }
}

// ---------------- cumprod along batch + first-occurrence argmax ----------------
__global__ __launch_bounds__(256) void k_final(const float* __restrict__ logits,
                                               const float* __restrict__ hazards,
                                               float* __restrict__ S,
                                               float* __restrict__ yhat) {
  const int c = blockIdx.x;
  const int t = threadIdx.x;
  __shared__ float pl[256];
  __shared__ float mv[256];
  __shared__ int   mi[256];
  float prod = 1.f;
  float best = -1e30f; int bi = 0;
  for (int i = 0; i < 16; ++i) {
    const int b = t * 16 + i;
    prod *= (1.f - hazards[b * 4 + c]);
    const float lg = logits[b * 4 + c];
    if (lg > best) { best = lg; bi = b; }
  }
  pl[t] = prod; mv[t] = best; mi[t] = bi;
  __syncthreads();
  for (int off = 1; off < 256; off <<= 1) {
    float cur  = pl[t];
    float prev = (t >= off) ? pl[t - off] : 1.f;
    __syncthreads();
    pl[t] = cur * prev;
    __syncthreads();
  }
  float s = (t == 0) ? 1.f : pl[t - 1];
  for (int i = 0; i < 16; ++i) {
    const int b = t * 16 + i;
    s *= (1.f - hazards[b * 4 + c]);
    S[b * 4 + c] = s;
  }
  for (int off = 128; off > 0; off >>= 1) {
    if (t < off) {
      float ov = mv[t + off]; int oi = mi[t + off];
      if (ov > mv[t] || (ov == mv[t] && oi < mi[t])) { mv[t] = ov; mi[t] = oi; }
    }
    __syncthreads();
  }
  if (t == 0) yhat[c] = (float)mi[0];
}

extern "C" void kernel_launch(void* const* d_in, const int* in_sizes, int n_in,
                              void* d_out, int out_size, void* d_ws, size_t ws_size,
                              hipStream_t stream) {
  (void)in_sizes; (void)n_in; (void)out_size; (void)ws_size;
  const float* x    = (const float*)d_in[0];
  const float* fc1w = (const float*)d_in[1];
  const float* fc1b = (const float*)d_in[2];
  const float* fc2w = (const float*)d_in[3];
  const float* fc2b = (const float*)d_in[4];
  const float* w1   = (const float*)d_in[5];
  const float* b1   = (const float*)d_in[6];
  const float* w2   = (const float*)d_in[7];
  const float* b2   = (const float*)d_in[8];
  const int*   comp = (const int*)d_in[9];

  char* ws = (char*)d_ws;
  const size_t MB = 1024ull * 1024ull;
  // region plan (peak 160MB):
  //   [0,32M)    xh     -> dead after GEMM1 -> w1Th
  //   [32M,64M)  w1mT   -> dead after GEMM1 -> part (fp16 2x16MB)
  //   [64M,96M)  out1h  -> dead after GEMM2 -> logits
  //   [96M,160M) out2h
  _Float16* xh     = (_Float16*)(ws + 0);
  _Float16* w1mT   = (_Float16*)(ws + 32 * MB);
  _Float16* out1h  = (_Float16*)(ws + 64 * MB);
  _Float16* out2h  = (_Float16*)(ws + 96 * MB);
  _Float16* w1Th   = (_Float16*)(ws + 0);
  _Float16* part   = (_Float16*)(ws + 32 * MB);
  float*    logits = (float*)(ws + 64 * MB);
  float*    outF   = (float*)d_out;

  hipFuncSetAttribute(reinterpret_cast<const void*>(k_gemm8<0>),
                      hipFuncAttributeMaxDynamicSharedMemorySize, 131072);
  hipFuncSetAttribute(reinterpret_cast<const void*>(k_gemm8<1>),
                      hipFuncAttributeMaxDynamicSharedMemorySize, 131072);

  // 1) pack x -> fp16
  k_pack_f16<<<(NB * NIN / 4) / 256, 256, 0, stream>>>(x, xh, NB * NIN / 4);
  // 2) pack (fc1_w * mask1)^T -> fp16 [P1][IN]
  k_packT<true><<<dim3(NP1 / 64, NIN / 64), 256, 0, stream>>>(fc1w, comp, w1mT, NIN, NP1);
  // 3) GEMM1: out1 = x @ fc1w_masked + fc1_b
  k_gemm8<0><<<(NB / 256) * (NP1 / 256), 512, 131072, stream>>>(
      xh, w1mT, fc1b, out1h, NB, NP1, NIN, NP1 / 256, 1);
  // 4) block-diagonal GEMM2 -> out2 fp16
  k_gemm2<<<(NB / 64) * (NNP / 32), 256, 0, stream>>>(out1h, fc2w, fc2b, out2h);
  // 5) pack w1^T -> fp16 [H][P2] (overlays dead xh)
  k_packT<false><<<dim3(NH / 64, NP2 / 64), 256, 0, stream>>>(w1, nullptr, w1Th, NP2, NH);
  // 6) GEMM3 split-K=2: fp16 partials = out2 @ w1 (overlays dead w1mT)
  k_gemm8<1><<<(NB / 256) * (NH / 256) * 2, 512, 131072, stream>>>(
      out2h, w1Th, nullptr, part, NB, NH, NP2, NH / 256, 2);
  // 7) fused: h = relu(p0+p1+b1); logits = h@w2+b2; hazards = sigmoid
  k_logits<<<NB / 4, 256, 0, stream>>>(part, b1, w2, b2, logits, outF);
  // 8) S and Y_hat
  k_final<<<4, 256, 0, stream>>>(logits, outF, outF + NB * 4, outF + 2 * NB * 4);
}

// Round 6
// 349.119 us; speedup vs baseline: 1.1107x; 1.0372x over previous
//
#include <hip/hip_runtime.h>
#include <cmath>

typedef _Float16 h8  __attribute__((ext_vector_type(8)));
typedef _Float16 h4v __attribute__((ext_vector_type(4)));
typedef float    f4  __attribute__((ext_vector_type(4)));

#define NB  4096
#define NIN 4096
#define NNP 512
#define NP1 4096
#define NP2 8192
#define NH  2048

__device__ __forceinline__ void g2l(const void* g, void* l) {
  __builtin_amdgcn_global_load_lds((const __attribute__((address_space(1))) void*)g,
                                   (__attribute__((address_space(3))) void*)l, 16, 0, 0);
}

// ---------------- pack f32 -> f16 (vectorized) ----------------
__global__ __launch_bounds__(256) void k_pack_f16(const float* __restrict__ in,
                                                  _Float16* __restrict__ out, int n4) {
  int i = blockIdx.x * 256 + threadIdx.x;
  if (i >= n4) return;
  f4 v = ((const f4*)in)[i];
  h4v o;
  o[0] = (_Float16)v[0]; o[1] = (_Float16)v[1];
  o[2] = (_Float16)v[2]; o[3] = (_Float16)v[3];
  ((h4v*)out)[i] = o;
}

// ---------------- transpose pack: out[n][k] = in[k][n] * optional mask ----------------
template<bool MASK>
__global__ __launch_bounds__(256) void k_packT(const float* __restrict__ in,
                                               const int* __restrict__ comp,
                                               _Float16* __restrict__ out, int K, int N) {
  __shared__ float tile[64][65];
  const int n0 = blockIdx.x * 64, k0 = blockIdx.y * 64;
  const int tx = threadIdx.x & 63, ty = threadIdx.x >> 6;
#pragma unroll
  for (int r = 0; r < 16; ++r) {
    int kk = r * 4 + ty;
    float v = in[(long)(k0 + kk) * N + n0 + tx];
    if (MASK) v *= (float)comp[(long)(k0 + kk) * NNP + ((n0 + tx) >> 3)];
    tile[kk][tx] = v;
  }
  __syncthreads();
#pragma unroll
  for (int r = 0; r < 16; ++r) {
    int nn = r * 4 + ty;
    out[(long)(n0 + nn) * K + k0 + tx] = (_Float16)tile[tx][nn];
  }
}

// ---------------- 256x256 fp16 GEMM, 16x16x32 frags, 8-phase schedule ----------------
// C = A[M,K] * BT[N,K]^T. EPI=0: C = acc + bias (fp16). EPI=1: fp16 split-K partial at ks*M*N.
// 8 waves (2m x 4n). Quadrant->half interleave (race-free, verified R5):
//   A row = mh*128 + wm*64 + m*16 + lh ; B row = nh*128 + wn*32 + n*16 + lh.
// LDS 128KB: 2buf x {A half0,half1 ; B half0,half1}, each half = [128 rows][128B] fp16.
// Zero-conflict geometry (verified R2): read col = (kq*64 + ls*16) ^ ((lh&7)<<4) --
// within every 8 consecutive lanes the 16B slots are a bijection over the 128B row.
// Staging: linear LDS dest + pre-swizzled global source col ((tid&7)^((tid>>3)&7))<<4.
// Iter = 2 K-tiles (BK=64), 8 phases, 1 half stage (2xg2l) per phase; vmcnt(6) @ P4/P8 only.
template<int EPI>
__global__ __launch_bounds__(512, 1) void k_gemm8(
    const _Float16* __restrict__ A, const _Float16* __restrict__ BT,
    const float* __restrict__ bias, _Float16* __restrict__ C,
    int M, int N, int K, int nbn, int ksplit) {
  extern __shared__ char smem[];
  // bijective XCD swizzle
  const int nwg = gridDim.x;
  const int q = nwg >> 3, r = nwg & 7;
  const int xcd = blockIdx.x & 7, idx = blockIdx.x >> 3;
  const int wg = (xcd < r ? xcd * (q + 1) : r * (q + 1) + (xcd - r) * q) + idx;
  const int tpk = nwg / ksplit;
  const int ks = wg / tpk;
  const int rem = wg - ks * tpk;
  const int bm = rem / nbn, bn = rem % nbn;
  const long m0 = (long)bm << 8, n0 = (long)bn << 8;
  const int Ks = K / ksplit;
  const int NT = Ks >> 6;              // BK=64

  const int tid = threadIdx.x;
  const int lane = tid & 63, w = tid >> 6;
  const int wm = w >> 2, wn = w & 3;
  const int lh = lane & 15, ls = lane >> 4;
  const int swz = (lh & 7) << 4;
  const int c0 = (ls * 16) ^ swz;        // kq=0 byte col within 128B row
  const int c1 = (64 + ls * 16) ^ swz;   // kq=1
  const int arow = (wm * 64 + lh) * 128;           // + mh*16384 + m_*2048
  const int brow = 32768 + (wn * 32 + lh) * 128;   // + nh*16384 + n_*2048

  // staging: lane tid supplies LDS (row = tid>>3 within the 64-row chunk, slot = tid&7);
  // source col pre-swizzled so LDS[row][slot] = global[row][slot ^ (row&7)].
  const long sKb = (long)K * 2;
  const int scb = (((tid & 7) ^ ((tid >> 3) & 7)) << 4);
  const char* Ag = (const char*)A + (m0 + (tid >> 3)) * sKb + (long)ks * Ks * 2 + scb;
  const char* Bg = (const char*)BT + (n0 + (tid >> 3)) * sKb + (long)ks * Ks * 2 + scb;
  const long h64 = 64 * sKb, h128 = 128 * sKb;
  const int lw = w << 10;

#define STAGE_A(buf, hh, kb) do { \
    const char* s_ = Ag + (hh) * h128 + (kb); \
    char* d_ = smem + (buf) * 65536 + (hh) * 16384 + lw; \
    g2l(s_, d_); g2l(s_ + h64, d_ + 8192); } while (0)
#define STAGE_B(buf, hh, kb) do { \
    const char* s_ = Bg + (hh) * h128 + (kb); \
    char* d_ = smem + (buf) * 65536 + 32768 + (hh) * 16384 + lw; \
    g2l(s_, d_); g2l(s_ + h64, d_ + 8192); } while (0)
#define RDA(buf, mh) do { \
    _Pragma("unroll") for (int m_ = 0; m_ < 4; ++m_) { \
      af[m_][0] = *(const h8*)(smem + (buf) * 65536 + (mh) * 16384 + arow + m_ * 2048 + c0); \
      af[m_][1] = *(const h8*)(smem + (buf) * 65536 + (mh) * 16384 + arow + m_ * 2048 + c1); } } while (0)
#define RDB(buf, nh) do { \
    _Pragma("unroll") for (int n_ = 0; n_ < 2; ++n_) { \
      bf[n_][0] = *(const h8*)(smem + (buf) * 65536 + (nh) * 16384 + brow + n_ * 2048 + c0); \
      bf[n_][1] = *(const h8*)(smem + (buf) * 65536 + (nh) * 16384 + brow + n_ * 2048 + c1); } } while (0)
#define MM(mh, nh) do { \
    _Pragma("unroll") for (int kq_ = 0; kq_ < 2; ++kq_) \
    _Pragma("unroll") for (int m_ = 0; m_ < 4; ++m_) \
    _Pragma("unroll") for (int n_ = 0; n_ < 2; ++n_) \
      acc[mh][nh][m_][n_] = __builtin_amdgcn_mfma_f32_16x16x32_f16(af[m_][kq_], bf[n_][kq_], acc[mh][nh][m_][n_], 0, 0, 0); } while (0)
#define BAR() asm volatile("s_barrier" ::: "memory")
#define LG0() asm volatile("s_waitcnt lgkmcnt(0)" ::: "memory")
#define LG8() asm volatile("s_waitcnt lgkmcnt(8)" ::: "memory")
#define VM6() asm volatile("s_waitcnt vmcnt(6)" ::: "memory")
#define PR1() __builtin_amdgcn_s_setprio(1)
#define PR0() __builtin_amdgcn_s_setprio(0)

  f4 acc[2][2][4][2] = {};   // [mh][nh][m][n]
  h8 af[4][2], bf[2][2];

  auto kc = [&](int t) -> long { return (long)(t < NT ? t : NT - 1) << 7; };

  // prologue: full tile0 (buf0) + {A0,B1,A1}(tile1, buf1); VM6 retires tile0's 4 halves
  STAGE_A(0, 0, kc(0));
  STAGE_B(0, 1, kc(0));
  STAGE_A(0, 1, kc(0));
  STAGE_B(0, 0, kc(0));
  STAGE_A(1, 0, kc(1));
  STAGE_B(1, 1, kc(1));
  STAGE_A(1, 1, kc(1));
  VM6(); BAR();

  for (int t2 = 0; t2 < NT; t2 += 2) {
    // ---------- K-tile t2 (buf0) ----------
    // P1: (mh0,nh0); stage B0(t2+1)->buf1 (slot last read at prev P8)
    RDA(0, 0); RDB(0, 0);
    STAGE_B(1, 0, kc(t2 + 1));
    LG8(); BAR(); LG0();
    PR1(); MM(0, 0); PR0(); BAR();
    // P2: (mh0,nh1); stage A0(t2+2)->buf0 (A-half0 last read at P1)
    RDB(0, 1);
    STAGE_A(0, 0, kc(t2 + 2));
    BAR(); LG0();
    PR1(); MM(0, 1); PR0(); BAR();
    // P3: (mh1,nh1); stage B1(t2+2)->buf0 (B-half1 last read at P2)
    RDA(0, 1);
    STAGE_B(0, 1, kc(t2 + 2));
    BAR(); LG0();
    PR1(); MM(1, 1); PR0(); BAR();
    // P4: (mh1,nh0) re-reads B-half0; stage A1(t2+2)->buf0 (A-half1 last read at P3)
    RDB(0, 0);
    STAGE_A(0, 1, kc(t2 + 2));
    BAR(); LG0();
    PR1(); MM(1, 0); PR0();
    VM6(); BAR();                       // tile t2+1 (buf1) fully landed
    // ---------- K-tile t2+1 (buf1) ----------
    // P5; stage B0(t2+2)->buf0 (B-half0 last read at P4)
    RDA(1, 0); RDB(1, 0);
    STAGE_B(0, 0, kc(t2 + 2));
    LG8(); BAR(); LG0();
    PR1(); MM(0, 0); PR0(); BAR();
    // P6; stage A0(t2+3)->buf1 (A-half0 last read at P5)
    RDB(1, 1);
    STAGE_A(1, 0, kc(t2 + 3));
    BAR(); LG0();
    PR1(); MM(0, 1); PR0(); BAR();
    // P7; stage B1(t2+3)->buf1 (B-half1 last read at P6)
    RDA(1, 1);
    STAGE_B(1, 1, kc(t2 + 3));
    BAR(); LG0();
    PR1(); MM(1, 1); PR0(); BAR();
    // P8; stage A1(t2+3)->buf1 (A-half1 last read at P7)
    RDB(1, 0);
    STAGE_A(1, 1, kc(t2 + 3));
    BAR(); LG0();
    PR1(); MM(1, 0); PR0();
    VM6(); BAR();                       // tile t2+2 (buf0) fully landed
  }

  // epilogue: 16x16 C/D layout col=lane&15, row=(lane>>4)*4+j
  _Float16* dst = (EPI == 1) ? (C + (long)ks * M * N) : C;
#pragma unroll
  for (int mh = 0; mh < 2; ++mh)
#pragma unroll
  for (int m = 0; m < 4; ++m) {
    const long r0 = m0 + mh * 128 + wm * 64 + m * 16 + ls * 4;
#pragma unroll
    for (int nh = 0; nh < 2; ++nh)
#pragma unroll
    for (int n = 0; n < 2; ++n) {
      const long c = n0 + nh * 128 + wn * 32 + n * 16 + lh;
      const float bv = (EPI == 0) ? bias[c] : 0.f;
#pragma unroll
      for (int j = 0; j < 4; ++j)
        dst[(r0 + j) * N + c] = (_Float16)(acc[mh][nh][m][n][j] + bv);
    }
  }
#undef STAGE_A
#undef STAGE_B
#undef RDA
#undef RDB
#undef MM
#undef BAR
#undef LG0
#undef LG8
#undef VM6
#undef PR1
#undef PR0
}

// ---------------- block-diagonal GEMM2 ----------------
__global__ __launch_bounds__(256) void k_gemm2(const _Float16* __restrict__ out1,
                                               const float* __restrict__ fc2w,
                                               const float* __restrict__ fc2b,
                                               _Float16* __restrict__ out2) {
  const int b0 = (blockIdx.x >> 4) * 64;
  const int p  = (blockIdx.x & 15) * 32 + (threadIdx.x & 31);
  const int bsub = threadIdx.x >> 5;
  f4 bb0 = *(const f4*)&fc2b[p * 16 + 0];
  f4 bb1 = *(const f4*)&fc2b[p * 16 + 4];
  f4 bb2 = *(const f4*)&fc2b[p * 16 + 8];
  f4 bb3 = *(const f4*)&fc2b[p * 16 + 12];
  for (int r = 0; r < 8; ++r) {
    const int b = b0 + r * 8 + bsub;
    h8 qv = *(const h8*)&out1[(long)b * NP1 + p * 8];
    f4 a0 = bb0, a1 = bb1, a2 = bb2, a3 = bb3;
#pragma unroll
    for (int i = 0; i < 8; ++i) {
      const float qi = (float)qv[i];
      const f4* wr = (const f4*)&fc2w[(long)(p * 8 + i) * NP2 + p * 16];
      a0 += qi * wr[0]; a1 += qi * wr[1]; a2 += qi * wr[2]; a3 += qi * wr[3];
    }
    h8 o0, o1;
#pragma unroll
    for (int u = 0; u < 4; ++u) {
      o0[u] = (_Float16)a0[u]; o0[4 + u] = (_Float16)a1[u];
      o1[u] = (_Float16)a2[u]; o1[4 + u] = (_Float16)a3[u];
    }
    h8* dstp = (h8*)&out2[(long)b * NP2 + p * 16];
    dstp[0] = o0; dstp[1] = o1;
  }
}

// ---------------- fused splitK-reduce + bias + relu + GEMM4 + sigmoid ----------------
__global__ __launch_bounds__(256) void k_logits(const _Float16* __restrict__ part,
                                                const float* __restrict__ b1,
                                                const float* __restrict__ w2,
                                                const float* __restrict__ b2,
                                                float* __restrict__ logits,
                                                float* __restrict__ hazards) {
  const int lane = threadIdx.x & 63;
  const int b = blockIdx.x * 4 + (threadIdx.x >> 6);
  const long off2 = (long)NB * NH;
  f4 acc = {0.f, 0.f, 0.f, 0.f};
  const _Float16* p0 = part + (long)b * NH;
  const _Float16* p1 = p0 + off2;
#pragma unroll
  for (int c4 = 0; c4 < 4; ++c4) {
    const int k0 = c4 * 512 + lane * 8;
    h8 a = *(const h8*)&p0[k0];
    h8 bb = *(const h8*)&p1[k0];
    f4 bva = *(const f4*)&b1[k0];
    f4 bvb = *(const f4*)&b1[k0 + 4];
#pragma unroll
    for (int u = 0; u < 8; ++u) {
      const float bias = (u < 4) ? bva[u] : bvb[u - 4];
      const float hv = fmaxf((float)a[u] + (float)bb[u] + bias, 0.f);
      acc += hv * *(const f4*)&w2[(long)(k0 + u) * 4];
    }
  }
#pragma unroll
  for (int off = 32; off > 0; off >>= 1) {
#pragma unroll
    for (int u = 0; u < 4; ++u) acc[u] += __shfl_xor(acc[u], off, 64);
  }
  if (lane == 0) {
    f4 lg = acc + *(const f4*)b2;
    ((f4*)logits)[b] = lg;
    f4 hz;
#pragma unroll
    for (int u = 0; u < 4; ++u) hz[u] = 1.f / (1.f + expf(-lg[u]));
    ((f4*)hazards)[b] = hz;
  }
}

// ---------------- cumprod along batch + first-occurrence argmax ----------------
__global__ __launch_bounds__(256) void k_final(const float* __restrict__ logits,
                                               const float* __restrict__ hazards,
                                               float* __restrict__ S,
                                               float* __restrict__ yhat) {
  const int c = blockIdx.x;
  const int t = threadIdx.x;
  __shared__ float pl[256];
  __shared__ float mv[256];
  __shared__ int   mi[256];
  float prod = 1.f;
  float best = -1e30f; int bi = 0;
  for (int i = 0; i < 16; ++i) {
    const int b = t * 16 + i;
    prod *= (1.f - hazards[b * 4 + c]);
    const float lg = logits[b * 4 + c];
    if (lg > best) { best = lg; bi = b; }
  }
  pl[t] = prod; mv[t] = best; mi[t] = bi;
  __syncthreads();
  for (int off = 1; off < 256; off <<= 1) {
    float cur  = pl[t];
    float prev = (t >= off) ? pl[t - off] : 1.f;
    __syncthreads();
    pl[t] = cur * prev;
    __syncthreads();
  }
  float s = (t == 0) ? 1.f : pl[t - 1];
  for (int i = 0; i < 16; ++i) {
    const int b = t * 16 + i;
    s *= (1.f - hazards[b * 4 + c]);
    S[b * 4 + c] = s;
  }
  for (int off = 128; off > 0; off >>= 1) {
    if (t < off) {
      float ov = mv[t + off]; int oi = mi[t + off];
      if (ov > mv[t] || (ov == mv[t] && oi < mi[t])) { mv[t] = ov; mi[t] = oi; }
    }
    __syncthreads();
  }
  if (t == 0) yhat[c] = (float)mi[0];
}

extern "C" void kernel_launch(void* const* d_in, const int* in_sizes, int n_in,
                              void* d_out, int out_size, void* d_ws, size_t ws_size,
                              hipStream_t stream) {
  (void)in_sizes; (void)n_in; (void)out_size; (void)ws_size;
  const float* x    = (const float*)d_in[0];
  const float* fc1w = (const float*)d_in[1];
  const float* fc1b = (const float*)d_in[2];
  const float* fc2w = (const float*)d_in[3];
  const float* fc2b = (const float*)d_in[4];
  const float* w1   = (const float*)d_in[5];
  const float* b1   = (const float*)d_in[6];
  const float* w2   = (const float*)d_in[7];
  const float* b2   = (const float*)d_in[8];
  const int*   comp = (const int*)d_in[9];

  char* ws = (char*)d_ws;
  const size_t MB = 1024ull * 1024ull;
  // region plan (peak 160MB):
  //   [0,32M)    xh     -> dead after GEMM1 -> w1Th
  //   [32M,64M)  w1mT   -> dead after GEMM1 -> part (fp16 2x16MB)
  //   [64M,96M)  out1h  -> dead after GEMM2 -> logits
  //   [96M,160M) out2h
  _Float16* xh     = (_Float16*)(ws + 0);
  _Float16* w1mT   = (_Float16*)(ws + 32 * MB);
  _Float16* out1h  = (_Float16*)(ws + 64 * MB);
  _Float16* out2h  = (_Float16*)(ws + 96 * MB);
  _Float16* w1Th   = (_Float16*)(ws + 0);
  _Float16* part   = (_Float16*)(ws + 32 * MB);
  float*    logits = (float*)(ws + 64 * MB);
  float*    outF   = (float*)d_out;

  hipFuncSetAttribute(reinterpret_cast<const void*>(k_gemm8<0>),
                      hipFuncAttributeMaxDynamicSharedMemorySize, 131072);
  hipFuncSetAttribute(reinterpret_cast<const void*>(k_gemm8<1>),
                      hipFuncAttributeMaxDynamicSharedMemorySize, 131072);

  // 1) pack x -> fp16
  k_pack_f16<<<(NB * NIN / 4) / 256, 256, 0, stream>>>(x, xh, NB * NIN / 4);
  // 2) pack (fc1_w * mask1)^T -> fp16 [P1][IN]
  k_packT<true><<<dim3(NP1 / 64, NIN / 64), 256, 0, stream>>>(fc1w, comp, w1mT, NIN, NP1);
  // 3) GEMM1: out1 = x @ fc1w_masked + fc1_b
  k_gemm8<0><<<(NB / 256) * (NP1 / 256), 512, 131072, stream>>>(
      xh, w1mT, fc1b, out1h, NB, NP1, NIN, NP1 / 256, 1);
  // 4) block-diagonal GEMM2 -> out2 fp16
  k_gemm2<<<(NB / 64) * (NNP / 32), 256, 0, stream>>>(out1h, fc2w, fc2b, out2h);
  // 5) pack w1^T -> fp16 [H][P2] (overlays dead xh)
  k_packT<false><<<dim3(NH / 64, NP2 / 64), 256, 0, stream>>>(w1, nullptr, w1Th, NP2, NH);
  // 6) GEMM3 split-K=2: fp16 partials = out2 @ w1 (overlays dead w1mT)
  k_gemm8<1><<<(NB / 256) * (NH / 256) * 2, 512, 131072, stream>>>(
      out2h, w1Th, nullptr, part, NB, NH, NP2, NH / 256, 2);
  // 7) fused: h = relu(p0+p1+b1); logits = h@w2+b2; hazards = sigmoid
  k_logits<<<NB / 4, 256, 0, stream>>>(part, b1, w2, b2, logits, outF);
  // 8) S and Y_hat
  k_final<<<4, 256, 0, stream>>>(logits, outF, outF + NB * 4, outF + 2 * NB * 4);
}

// Round 7
// 336.918 us; speedup vs baseline: 1.1509x; 1.0362x over previous
//
#include <hip/hip_runtime.h>
#include <cmath>

typedef _Float16 h8  __attribute__((ext_vector_type(8)));
typedef _Float16 h4v __attribute__((ext_vector_type(4)));
typedef float    f4  __attribute__((ext_vector_type(4)));

#define NB  4096
#define NIN 4096
#define NNP 512
#define NP1 4096
#define NP2 8192
#define NH  2048

__device__ __forceinline__ void g2l(const void* g, void* l) {
  __builtin_amdgcn_global_load_lds((const __attribute__((address_space(1))) void*)g,
                                   (__attribute__((address_space(3))) void*)l, 16, 0, 0);
}

// ---------------- pack f32 -> f16 (vectorized) ----------------
__global__ __launch_bounds__(256) void k_pack_f16(const float* __restrict__ in,
                                                  _Float16* __restrict__ out, int n4) {
  int i = blockIdx.x * 256 + threadIdx.x;
  if (i >= n4) return;
  f4 v = ((const f4*)in)[i];
  h4v o;
  o[0] = (_Float16)v[0]; o[1] = (_Float16)v[1];
  o[2] = (_Float16)v[2]; o[3] = (_Float16)v[3];
  ((h4v*)out)[i] = o;
}

// ---------------- transpose pack: out[n][k] = in[k][n] * optional mask ----------------
template<bool MASK>
__global__ __launch_bounds__(256) void k_packT(const float* __restrict__ in,
                                               const int* __restrict__ comp,
                                               _Float16* __restrict__ out, int K, int N) {
  __shared__ float tile[64][65];
  const int n0 = blockIdx.x * 64, k0 = blockIdx.y * 64;
  const int tx = threadIdx.x & 63, ty = threadIdx.x >> 6;
#pragma unroll
  for (int r = 0; r < 16; ++r) {
    int kk = r * 4 + ty;
    float v = in[(long)(k0 + kk) * N + n0 + tx];
    if (MASK) v *= (float)comp[(long)(k0 + kk) * NNP + ((n0 + tx) >> 3)];
    tile[kk][tx] = v;
  }
  __syncthreads();
#pragma unroll
  for (int r = 0; r < 16; ++r) {
    int nn = r * 4 + ty;
    out[(long)(n0 + nn) * K + k0 + tx] = (_Float16)tile[tx][nn];
  }
}

// ---------------- 256x256 fp16 GEMM, 16x16x32 frags, read-ahead pipelined 8-phase ----------------
// C = A[M,K] * BT[N,K]^T. EPI=0: C = acc + bias (fp16). EPI=1: fp16 split-K partial at ks*M*N.
// 8 waves (2m x 4n). A row = mh*128 + wm*64 + m*16 + lh ; B row = nh*128 + wn*32 + n*16 + lh.
// LDS 128KB: 2buf x {A half0,half1 ; B half0,half1}, each half [128 rows][128B] fp16.
// Zero-conflict read col (verified R6): (kq*64 + ls*16) ^ ((lh&7)<<4); staging = linear LDS
// dest + pre-swizzled global source.
// Pipelining: each phase's ds_reads load the NEXT phase's fragments into alternate register
// sets (afA/afB, bfA/bfB; B parity swaps per tile) -> MFMA never waits on LDS latency.
// Stages for tile t+2 spread P1..P4 of tile t; one vmcnt(6) per K-tile (ledger: 14 out, retires
// exactly the next tile's 8 stages). Plain ds_reads: compiler emits counted lgkm waits.
template<int EPI>
__global__ __launch_bounds__(512, 1) void k_gemm8(
    const _Float16* __restrict__ A, const _Float16* __restrict__ BT,
    const float* __restrict__ bias, _Float16* __restrict__ C,
    int M, int N, int K, int nbn, int ksplit) {
  extern __shared__ char smem[];
  // bijective XCD swizzle
  const int nwg = gridDim.x;
  const int q = nwg >> 3, r = nwg & 7;
  const int xcd = blockIdx.x & 7, idx = blockIdx.x >> 3;
  const int wg = (xcd < r ? xcd * (q + 1) : r * (q + 1) + (xcd - r) * q) + idx;
  const int tpk = nwg / ksplit;
  const int ks = wg / tpk;
  const int rem = wg - ks * tpk;
  const int bm = rem / nbn, bn = rem % nbn;
  const long m0 = (long)bm << 8, n0 = (long)bn << 8;
  const int Ks = K / ksplit;
  const int NT = Ks >> 6;              // BK=64, NT even (K multiples of 128)

  const int tid = threadIdx.x;
  const int lane = tid & 63, w = tid >> 6;
  const int wm = w >> 2, wn = w & 3;
  const int lh = lane & 15, ls = lane >> 4;
  const int swz = (lh & 7) << 4;
  const int c0 = (ls * 16) ^ swz;
  const int c1 = (64 + ls * 16) ^ swz;
  const int arow = (wm * 64 + lh) * 128;           // + mh*16384 + m_*2048
  const int brow = 32768 + (wn * 32 + lh) * 128;   // + nh*16384 + n_*2048

  const long sKb = (long)K * 2;
  const int scb = (((tid & 7) ^ ((tid >> 3) & 7)) << 4);
  const char* Ag = (const char*)A + (m0 + (tid >> 3)) * sKb + (long)ks * Ks * 2 + scb;
  const char* Bg = (const char*)BT + (n0 + (tid >> 3)) * sKb + (long)ks * Ks * 2 + scb;
  const long h64 = 64 * sKb, h128 = 128 * sKb;
  const int lw = w << 10;

#define STAGE_A(buf, hh, kb) do { \
    const char* s_ = Ag + (hh) * h128 + (kb); \
    char* d_ = smem + (buf) * 65536 + (hh) * 16384 + lw; \
    g2l(s_, d_); g2l(s_ + h64, d_ + 8192); } while (0)
#define STAGE_B(buf, hh, kb) do { \
    const char* s_ = Bg + (hh) * h128 + (kb); \
    char* d_ = smem + (buf) * 65536 + 32768 + (hh) * 16384 + lw; \
    g2l(s_, d_); g2l(s_ + h64, d_ + 8192); } while (0)
#define READ_A(dst, buf, mh) do { \
    _Pragma("unroll") for (int m_ = 0; m_ < 4; ++m_) { \
      dst[m_][0] = *(const h8*)(smem + (buf) * 65536 + (mh) * 16384 + arow + m_ * 2048 + c0); \
      dst[m_][1] = *(const h8*)(smem + (buf) * 65536 + (mh) * 16384 + arow + m_ * 2048 + c1); } } while (0)
#define READ_B(dst, buf, nh) do { \
    _Pragma("unroll") for (int n_ = 0; n_ < 2; ++n_) { \
      dst[n_][0] = *(const h8*)(smem + (buf) * 65536 + (nh) * 16384 + brow + n_ * 2048 + c0); \
      dst[n_][1] = *(const h8*)(smem + (buf) * 65536 + (nh) * 16384 + brow + n_ * 2048 + c1); } } while (0)
#define MM(mh, nh, aset, bset) do { \
    _Pragma("unroll") for (int kq_ = 0; kq_ < 2; ++kq_) \
    _Pragma("unroll") for (int m_ = 0; m_ < 4; ++m_) \
    _Pragma("unroll") for (int n_ = 0; n_ < 2; ++n_) \
      acc[mh][nh][m_][n_] = __builtin_amdgcn_mfma_f32_16x16x32_f16(aset[m_][kq_], bset[n_][kq_], acc[mh][nh][m_][n_], 0, 0, 0); } while (0)
#define BAR() asm volatile("s_barrier" ::: "memory")
#define VM6() asm volatile("s_waitcnt vmcnt(6)" ::: "memory")
#define VM8() asm volatile("s_waitcnt vmcnt(8)" ::: "memory")
#define PR1() __builtin_amdgcn_s_setprio(1)
#define PR0() __builtin_amdgcn_s_setprio(0)

  f4 acc[2][2][4][2] = {};   // [mh][nh][m][n]
  h8 afA[4][2], afB[4][2];   // A half0 / half1 fragment sets
  h8 bfA[2][2], bfB[2][2];   // B sets: even tiles B0->bfA,B1->bfB; odd tiles swapped

  auto kc = [&](int t) -> long { return (long)(t < NT ? t : NT - 1) << 7; };

  // prologue: stage tile0->buf0 (8 g2l), tile1->buf1 (8 g2l); retire tile0; preload A0,B0(t0)
  STAGE_A(0, 0, kc(0)); STAGE_B(0, 0, kc(0)); STAGE_B(0, 1, kc(0)); STAGE_A(0, 1, kc(0));
  STAGE_A(1, 0, kc(1)); STAGE_B(1, 0, kc(1)); STAGE_B(1, 1, kc(1)); STAGE_A(1, 1, kc(1));
  VM8();
  BAR();
  READ_A(afA, 0, 0);
  READ_B(bfA, 0, 0);

  for (int t2 = 0; t2 < NT; t2 += 2) {
    // ================= even tile t2 (buf0) =================
    // P1: MFMA(A0,B0); read B1(t2) ahead; stage A0(t2+2)
    BAR();
    READ_B(bfB, 0, 1);
    STAGE_A(0, 0, kc(t2 + 2));
    PR1(); MM(0, 0, afA, bfA); PR0();
    // P2: MFMA(A0,B1); read A1(t2) ahead; stage B1(t2+2)
    BAR();
    READ_A(afB, 0, 1);
    STAGE_B(0, 1, kc(t2 + 2));
    PR1(); MM(0, 1, afA, bfB); PR0();
    // P3: MFMA(A1,B1); gate tile t2+1 (vmcnt ledger = 14 -> retire its 8); read A0(t2+1)
    BAR();
    STAGE_A(0, 1, kc(t2 + 2));
    VM6();
    READ_A(afA, 1, 0);
    PR1(); MM(1, 1, afB, bfB); PR0();
    // P4: MFMA(A1,B0); read B0(t2+1)->bfB (odd parity); stage B0(t2+2)
    BAR();
    READ_B(bfB, 1, 0);
    STAGE_B(0, 0, kc(t2 + 2));
    PR1(); MM(1, 0, afB, bfA); PR0();
    // ================= odd tile t2+1 (buf1) =================
    // P5: MFMA(A0,B0=bfB); read B1(t2+1)->bfA; stage A0(t2+3)
    BAR();
    READ_B(bfA, 1, 1);
    STAGE_A(1, 0, kc(t2 + 3));
    PR1(); MM(0, 0, afA, bfB); PR0();
    // P6: MFMA(A0,B1=bfA); read A1(t2+1); stage B1(t2+3)
    BAR();
    READ_A(afB, 1, 1);
    STAGE_B(1, 1, kc(t2 + 3));
    PR1(); MM(0, 1, afA, bfA); PR0();
    // P7: MFMA(A1,B1=bfA); gate tile t2+2 (retire P1..P4 stages); read A0(t2+2)
    BAR();
    STAGE_A(1, 1, kc(t2 + 3));
    VM6();
    READ_A(afA, 0, 0);
    PR1(); MM(1, 1, afB, bfA); PR0();
    // P8: MFMA(A1,B0=bfB); read B0(t2+2)->bfA (even parity); stage B0(t2+3)
    BAR();
    READ_B(bfA, 0, 0);
    STAGE_B(1, 0, kc(t2 + 3));
    PR1(); MM(1, 0, afB, bfB); PR0();
  }

  // epilogue: 16x16 C/D layout col=lane&15, row=(lane>>4)*4+j
  _Float16* dst = (EPI == 1) ? (C + (long)ks * M * N) : C;
#pragma unroll
  for (int mh = 0; mh < 2; ++mh)
#pragma unroll
  for (int m = 0; m < 4; ++m) {
    const long r0 = m0 + mh * 128 + wm * 64 + m * 16 + ls * 4;
#pragma unroll
    for (int nh = 0; nh < 2; ++nh)
#pragma unroll
    for (int n = 0; n < 2; ++n) {
      const long c = n0 + nh * 128 + wn * 32 + n * 16 + lh;
      const float bv = (EPI == 0) ? bias[c] : 0.f;
#pragma unroll
      for (int j = 0; j < 4; ++j)
        dst[(r0 + j) * N + c] = (_Float16)(acc[mh][nh][m][n][j] + bv);
    }
  }
#undef STAGE_A
#undef STAGE_B
#undef READ_A
#undef READ_B
#undef MM
#undef BAR
#undef VM6
#undef VM8
#undef PR1
#undef PR0
}

// ---------------- block-diagonal GEMM2 ----------------
__global__ __launch_bounds__(256) void k_gemm2(const _Float16* __restrict__ out1,
                                               const float* __restrict__ fc2w,
                                               const float* __restrict__ fc2b,
                                               _Float16* __restrict__ out2) {
  const int b0 = (blockIdx.x >> 4) * 64;
  const int p  = (blockIdx.x & 15) * 32 + (threadIdx.x & 31);
  const int bsub = threadIdx.x >> 5;
  f4 bb0 = *(const f4*)&fc2b[p * 16 + 0];
  f4 bb1 = *(const f4*)&fc2b[p * 16 + 4];
  f4 bb2 = *(const f4*)&fc2b[p * 16 + 8];
  f4 bb3 = *(const f4*)&fc2b[p * 16 + 12];
  for (int r = 0; r < 8; ++r) {
    const int b = b0 + r * 8 + bsub;
    h8 qv = *(const h8*)&out1[(long)b * NP1 + p * 8];
    f4 a0 = bb0, a1 = bb1, a2 = bb2, a3 = bb3;
#pragma unroll
    for (int i = 0; i < 8; ++i) {
      const float qi = (float)qv[i];
      const f4* wr = (const f4*)&fc2w[(long)(p * 8 + i) * NP2 + p * 16];
      a0 += qi * wr[0]; a1 += qi * wr[1]; a2 += qi * wr[2]; a3 += qi * wr[3];
    }
    h8 o0, o1;
#pragma unroll
    for (int u = 0; u < 4; ++u) {
      o0[u] = (_Float16)a0[u]; o0[4 + u] = (_Float16)a1[u];
      o1[u] = (_Float16)a2[u]; o1[4 + u] = (_Float16)a3[u];
    }
    h8* dstp = (h8*)&out2[(long)b * NP2 + p * 16];
    dstp[0] = o0; dstp[1] = o1;
  }
}

// ---------------- fused splitK-reduce + bias + relu + GEMM4 + sigmoid ----------------
__global__ __launch_bounds__(256) void k_logits(const _Float16* __restrict__ part,
                                                const float* __restrict__ b1,
                                                const float* __restrict__ w2,
                                                const float* __restrict__ b2,
                                                float* __restrict__ logits,
                                                float* __restrict__ hazards) {
  const int lane = threadIdx.x & 63;
  const int b = blockIdx.x * 4 + (threadIdx.x >> 6);
  const long off2 = (long)NB * NH;
  f4 acc = {0.f, 0.f, 0.f, 0.f};
  const _Float16* p0 = part + (long)b * NH;
  const _Float16* p1 = p0 + off2;
#pragma unroll
  for (int c4 = 0; c4 < 4; ++c4) {
    const int k0 = c4 * 512 + lane * 8;
    h8 a = *(const h8*)&p0[k0];
    h8 bb = *(const h8*)&p1[k0];
    f4 bva = *(const f4*)&b1[k0];
    f4 bvb = *(const f4*)&b1[k0 + 4];
#pragma unroll
    for (int u = 0; u < 8; ++u) {
      const float bias = (u < 4) ? bva[u] : bvb[u - 4];
      const float hv = fmaxf((float)a[u] + (float)bb[u] + bias, 0.f);
      acc += hv * *(const f4*)&w2[(long)(k0 + u) * 4];
    }
  }
#pragma unroll
  for (int off = 32; off > 0; off >>= 1) {
#pragma unroll
    for (int u = 0; u < 4; ++u) acc[u] += __shfl_xor(acc[u], off, 64);
  }
  if (lane == 0) {
    f4 lg = acc + *(const f4*)b2;
    ((f4*)logits)[b] = lg;
    f4 hz;
#pragma unroll
    for (int u = 0; u < 4; ++u) hz[u] = 1.f / (1.f + expf(-lg[u]));
    ((f4*)hazards)[b] = hz;
  }
}

// ---------------- cumprod along batch + first-occurrence argmax ----------------
__global__ __launch_bounds__(256) void k_final(const float* __restrict__ logits,
                                               const float* __restrict__ hazards,
                                               float* __restrict__ S,
                                               float* __restrict__ yhat) {
  const int c = blockIdx.x;
  const int t = threadIdx.x;
  __shared__ float pl[256];
  __shared__ float mv[256];
  __shared__ int   mi[256];
  float prod = 1.f;
  float best = -1e30f; int bi = 0;
  for (int i = 0; i < 16; ++i) {
    const int b = t * 16 + i;
    prod *= (1.f - hazards[b * 4 + c]);
    const float lg = logits[b * 4 + c];
    if (lg > best) { best = lg; bi = b; }
  }
  pl[t] = prod; mv[t] = best; mi[t] = bi;
  __syncthreads();
  for (int off = 1; off < 256; off <<= 1) {
    float cur  = pl[t];
    float prev = (t >= off) ? pl[t - off] : 1.f;
    __syncthreads();
    pl[t] = cur * prev;
    __syncthreads();
  }
  float s = (t == 0) ? 1.f : pl[t - 1];
  for (int i = 0; i < 16; ++i) {
    const int b = t * 16 + i;
    s *= (1.f - hazards[b * 4 + c]);
    S[b * 4 + c] = s;
  }
  for (int off = 128; off > 0; off >>= 1) {
    if (t < off) {
      float ov = mv[t + off]; int oi = mi[t + off];
      if (ov > mv[t] || (ov == mv[t] && oi < mi[t])) { mv[t] = ov; mi[t] = oi; }
    }
    __syncthreads();
  }
  if (t == 0) yhat[c] = (float)mi[0];
}

extern "C" void kernel_launch(void* const* d_in, const int* in_sizes, int n_in,
                              void* d_out, int out_size, void* d_ws, size_t ws_size,
                              hipStream_t stream) {
  (void)in_sizes; (void)n_in; (void)out_size; (void)ws_size;
  const float* x    = (const float*)d_in[0];
  const float* fc1w = (const float*)d_in[1];
  const float* fc1b = (const float*)d_in[2];
  const float* fc2w = (const float*)d_in[3];
  const float* fc2b = (const float*)d_in[4];
  const float* w1   = (const float*)d_in[5];
  const float* b1   = (const float*)d_in[6];
  const float* w2   = (const float*)d_in[7];
  const float* b2   = (const float*)d_in[8];
  const int*   comp = (const int*)d_in[9];

  char* ws = (char*)d_ws;
  const size_t MB = 1024ull * 1024ull;
  // region plan (peak 160MB):
  //   [0,32M)    xh     -> dead after GEMM1 -> w1Th
  //   [32M,64M)  w1mT   -> dead after GEMM1 -> part (fp16 2x16MB)
  //   [64M,96M)  out1h  -> dead after GEMM2 -> logits
  //   [96M,160M) out2h
  _Float16* xh     = (_Float16*)(ws + 0);
  _Float16* w1mT   = (_Float16*)(ws + 32 * MB);
  _Float16* out1h  = (_Float16*)(ws + 64 * MB);
  _Float16* out2h  = (_Float16*)(ws + 96 * MB);
  _Float16* w1Th   = (_Float16*)(ws + 0);
  _Float16* part   = (_Float16*)(ws + 32 * MB);
  float*    logits = (float*)(ws + 64 * MB);
  float*    outF   = (float*)d_out;

  hipFuncSetAttribute(reinterpret_cast<const void*>(k_gemm8<0>),
                      hipFuncAttributeMaxDynamicSharedMemorySize, 131072);
  hipFuncSetAttribute(reinterpret_cast<const void*>(k_gemm8<1>),
                      hipFuncAttributeMaxDynamicSharedMemorySize, 131072);

  // 1) pack x -> fp16
  k_pack_f16<<<(NB * NIN / 4) / 256, 256, 0, stream>>>(x, xh, NB * NIN / 4);
  // 2) pack (fc1_w * mask1)^T -> fp16 [P1][IN]
  k_packT<true><<<dim3(NP1 / 64, NIN / 64), 256, 0, stream>>>(fc1w, comp, w1mT, NIN, NP1);
  // 3) GEMM1: out1 = x @ fc1w_masked + fc1_b
  k_gemm8<0><<<(NB / 256) * (NP1 / 256), 512, 131072, stream>>>(
      xh, w1mT, fc1b, out1h, NB, NP1, NIN, NP1 / 256, 1);
  // 4) block-diagonal GEMM2 -> out2 fp16
  k_gemm2<<<(NB / 64) * (NNP / 32), 256, 0, stream>>>(out1h, fc2w, fc2b, out2h);
  // 5) pack w1^T -> fp16 [H][P2] (overlays dead xh)
  k_packT<false><<<dim3(NH / 64, NP2 / 64), 256, 0, stream>>>(w1, nullptr, w1Th, NP2, NH);
  // 6) GEMM3 split-K=2: fp16 partials = out2 @ w1 (overlays dead w1mT)
  k_gemm8<1><<<(NB / 256) * (NH / 256) * 2, 512, 131072, stream>>>(
      out2h, w1Th, nullptr, part, NB, NH, NP2, NH / 256, 2);
  // 7) fused: h = relu(p0+p1+b1); logits = h@w2+b2; hazards = sigmoid
  k_logits<<<NB / 4, 256, 0, stream>>>(part, b1, w2, b2, logits, outF);
  // 8) S and Y_hat
  k_final<<<4, 256, 0, stream>>>(logits, outF, outF + NB * 4, outF + 2 * NB * 4);
}

// Round 8
// 336.805 us; speedup vs baseline: 1.1513x; 1.0003x over previous
//
#include <hip/hip_runtime.h>
#include <cmath>

typedef _Float16 h8  __attribute__((ext_vector_type(8)));
typedef _Float16 h4v __attribute__((ext_vector_type(4)));
typedef float    f4  __attribute__((ext_vector_type(4)));

#define NB  4096
#define NIN 4096
#define NNP 512
#define NP1 4096
#define NP2 8192
#define NH  2048

__device__ __forceinline__ void g2l(const void* g, void* l) {
  __builtin_amdgcn_global_load_lds((const __attribute__((address_space(1))) void*)g,
                                   (__attribute__((address_space(3))) void*)l, 16, 0, 0);
}

// ---------------- pack f32 -> f16 (vectorized) ----------------
__global__ __launch_bounds__(256) void k_pack_f16(const float* __restrict__ in,
                                                  _Float16* __restrict__ out, int n4) {
  int i = blockIdx.x * 256 + threadIdx.x;
  if (i >= n4) return;
  f4 v = ((const f4*)in)[i];
  h4v o;
  o[0] = (_Float16)v[0]; o[1] = (_Float16)v[1];
  o[2] = (_Float16)v[2]; o[3] = (_Float16)v[3];
  ((h4v*)out)[i] = o;
}

// ---------------- transpose pack: out[n][k] = in[k][n] * optional mask ----------------
template<bool MASK>
__global__ __launch_bounds__(256) void k_packT(const float* __restrict__ in,
                                               const int* __restrict__ comp,
                                               _Float16* __restrict__ out, int K, int N) {
  __shared__ float tile[64][65];
  const int n0 = blockIdx.x * 64, k0 = blockIdx.y * 64;
  const int tx = threadIdx.x & 63, ty = threadIdx.x >> 6;
#pragma unroll
  for (int r = 0; r < 16; ++r) {
    int kk = r * 4 + ty;
    float v = in[(long)(k0 + kk) * N + n0 + tx];
    if (MASK) v *= (float)comp[(long)(k0 + kk) * NNP + ((n0 + tx) >> 3)];
    tile[kk][tx] = v;
  }
  __syncthreads();
#pragma unroll
  for (int r = 0; r < 16; ++r) {
    int nn = r * 4 + ty;
    out[(long)(n0 + nn) * K + k0 + tx] = (_Float16)tile[tx][nn];
  }
}

// ---------------- 256x256 fp16 GEMM, 16x16x32 frags, read-ahead pipelined 8-phase ----------------
// C = A[M,K] * BT[N,K]^T. EPI=0: C = acc + bias (fp16). EPI=1: fp16 split-K partial at ks*M*N.
// 8 waves (2m x 4n). A row = mh*128 + wm*64 + m*16 + lh ; B row = nh*128 + wn*32 + n*16 + lh.
// LDS 128KB: 2buf x {A half0,half1 ; B half0,half1}, each half [128 rows][128B] fp16.
// Zero-conflict read col (verified R6): (kq*64 + ls*16) ^ ((lh&7)<<4); staging = linear LDS
// dest + pre-swizzled global source.
// Pipelining: each phase's ds_reads load the NEXT phase's fragments into alternate register
// sets (afA/afB, bfA/bfB; B parity swaps per tile) -> MFMA never waits on LDS latency.
// Stages for tile t+2 spread P1..P4 of tile t; one vmcnt(6) per K-tile (ledger: 14 out, retires
// exactly the next tile's 8 stages). Plain ds_reads: compiler emits counted lgkm waits.
template<int EPI>
__global__ __launch_bounds__(512, 1) void k_gemm8(
    const _Float16* __restrict__ A, const _Float16* __restrict__ BT,
    const float* __restrict__ bias, _Float16* __restrict__ C,
    int M, int N, int K, int nbn, int ksplit) {
  extern __shared__ char smem[];
  // bijective XCD swizzle
  const int nwg = gridDim.x;
  const int q = nwg >> 3, r = nwg & 7;
  const int xcd = blockIdx.x & 7, idx = blockIdx.x >> 3;
  const int wg = (xcd < r ? xcd * (q + 1) : r * (q + 1) + (xcd - r) * q) + idx;
  const int tpk = nwg / ksplit;
  const int ks = wg / tpk;
  const int rem = wg - ks * tpk;
  const int bm = rem / nbn, bn = rem % nbn;
  const long m0 = (long)bm << 8, n0 = (long)bn << 8;
  const int Ks = K / ksplit;
  const int NT = Ks >> 6;              // BK=64, NT even (K multiples of 128)

  const int tid = threadIdx.x;
  const int lane = tid & 63, w = tid >> 6;
  const int wm = w >> 2, wn = w & 3;
  const int lh = lane & 15, ls = lane >> 4;
  const int swz = (lh & 7) << 4;
  const int c0 = (ls * 16) ^ swz;
  const int c1 = (64 + ls * 16) ^ swz;
  const int arow = (wm * 64 + lh) * 128;           // + mh*16384 + m_*2048
  const int brow = 32768 + (wn * 32 + lh) * 128;   // + nh*16384 + n_*2048

  const long sKb = (long)K * 2;
  const int scb = (((tid & 7) ^ ((tid >> 3) & 7)) << 4);
  const char* Ag = (const char*)A + (m0 + (tid >> 3)) * sKb + (long)ks * Ks * 2 + scb;
  const char* Bg = (const char*)BT + (n0 + (tid >> 3)) * sKb + (long)ks * Ks * 2 + scb;
  const long h64 = 64 * sKb, h128 = 128 * sKb;
  const int lw = w << 10;

#define STAGE_A(buf, hh, kb) do { \
    const char* s_ = Ag + (hh) * h128 + (kb); \
    char* d_ = smem + (buf) * 65536 + (hh) * 16384 + lw; \
    g2l(s_, d_); g2l(s_ + h64, d_ + 8192); } while (0)
#define STAGE_B(buf, hh, kb) do { \
    const char* s_ = Bg + (hh) * h128 + (kb); \
    char* d_ = smem + (buf) * 65536 + 32768 + (hh) * 16384 + lw; \
    g2l(s_, d_); g2l(s_ + h64, d_ + 8192); } while (0)
#define READ_A(dst, buf, mh) do { \
    _Pragma("unroll") for (int m_ = 0; m_ < 4; ++m_) { \
      dst[m_][0] = *(const h8*)(smem + (buf) * 65536 + (mh) * 16384 + arow + m_ * 2048 + c0); \
      dst[m_][1] = *(const h8*)(smem + (buf) * 65536 + (mh) * 16384 + arow + m_ * 2048 + c1); } } while (0)
#define READ_B(dst, buf, nh) do { \
    _Pragma("unroll") for (int n_ = 0; n_ < 2; ++n_) { \
      dst[n_][0] = *(const h8*)(smem + (buf) * 65536 + (nh) * 16384 + brow + n_ * 2048 + c0); \
      dst[n_][1] = *(const h8*)(smem + (buf) * 65536 + (nh) * 16384 + brow + n_ * 2048 + c1); } } while (0)
#define MM(mh, nh, aset, bset) do { \
    _Pragma("unroll") for (int kq_ = 0; kq_ < 2; ++kq_) \
    _Pragma("unroll") for (int m_ = 0; m_ < 4; ++m_) \
    _Pragma("unroll") for (int n_ = 0; n_ < 2; ++n_) \
      acc[mh][nh][m_][n_] = __builtin_amdgcn_mfma_f32_16x16x32_f16(aset[m_][kq_], bset[n_][kq_], acc[mh][nh][m_][n_], 0, 0, 0); } while (0)
#define BAR() asm volatile("s_barrier" ::: "memory")
#define VM6() asm volatile("s_waitcnt vmcnt(6)" ::: "memory")
#define VM8() asm volatile("s_waitcnt vmcnt(8)" ::: "memory")
#define PR1() __builtin_amdgcn_s_setprio(1)
#define PR0() __builtin_amdgcn_s_setprio(0)

  f4 acc[2][2][4][2] = {};   // [mh][nh][m][n]
  h8 afA[4][2], afB[4][2];   // A half0 / half1 fragment sets
  h8 bfA[2][2], bfB[2][2];   // B sets: even tiles B0->bfA,B1->bfB; odd tiles swapped

  auto kc = [&](int t) -> long { return (long)(t < NT ? t : NT - 1) << 7; };

  // prologue: stage tile0->buf0 (8 g2l), tile1->buf1 (8 g2l); retire tile0; preload A0,B0(t0)
  STAGE_A(0, 0, kc(0)); STAGE_B(0, 0, kc(0)); STAGE_B(0, 1, kc(0)); STAGE_A(0, 1, kc(0));
  STAGE_A(1, 0, kc(1)); STAGE_B(1, 0, kc(1)); STAGE_B(1, 1, kc(1)); STAGE_A(1, 1, kc(1));
  VM8();
  BAR();
  READ_A(afA, 0, 0);
  READ_B(bfA, 0, 0);

  for (int t2 = 0; t2 < NT; t2 += 2) {
    // ================= even tile t2 (buf0) =================
    // P1: MFMA(A0,B0); read B1(t2) ahead; stage A0(t2+2)
    BAR();
    READ_B(bfB, 0, 1);
    STAGE_A(0, 0, kc(t2 + 2));
    PR1(); MM(0, 0, afA, bfA); PR0();
    // P2: MFMA(A0,B1); read A1(t2) ahead; stage B1(t2+2)
    BAR();
    READ_A(afB, 0, 1);
    STAGE_B(0, 1, kc(t2 + 2));
    PR1(); MM(0, 1, afA, bfB); PR0();
    // P3: MFMA(A1,B1); gate tile t2+1 (vmcnt ledger = 14 -> retire its 8); read A0(t2+1)
    BAR();
    STAGE_A(0, 1, kc(t2 + 2));
    VM6();
    READ_A(afA, 1, 0);
    PR1(); MM(1, 1, afB, bfB); PR0();
    // P4: MFMA(A1,B0); read B0(t2+1)->bfB (odd parity); stage B0(t2+2)
    BAR();
    READ_B(bfB, 1, 0);
    STAGE_B(0, 0, kc(t2 + 2));
    PR1(); MM(1, 0, afB, bfA); PR0();
    // ================= odd tile t2+1 (buf1) =================
    // P5: MFMA(A0,B0=bfB); read B1(t2+1)->bfA; stage A0(t2+3)
    BAR();
    READ_B(bfA, 1, 1);
    STAGE_A(1, 0, kc(t2 + 3));
    PR1(); MM(0, 0, afA, bfB); PR0();
    // P6: MFMA(A0,B1=bfA); read A1(t2+1); stage B1(t2+3)
    BAR();
    READ_A(afB, 1, 1);
    STAGE_B(1, 1, kc(t2 + 3));
    PR1(); MM(0, 1, afA, bfA); PR0();
    // P7: MFMA(A1,B1=bfA); gate tile t2+2 (retire P1..P4 stages); read A0(t2+2)
    BAR();
    STAGE_A(1, 1, kc(t2 + 3));
    VM6();
    READ_A(afA, 0, 0);
    PR1(); MM(1, 1, afB, bfA); PR0();
    // P8: MFMA(A1,B0=bfB); read B0(t2+2)->bfA (even parity); stage B0(t2+3)
    BAR();
    READ_B(bfA, 0, 0);
    STAGE_B(1, 0, kc(t2 + 3));
    PR1(); MM(1, 0, afB, bfB); PR0();
  }

  // epilogue: 16x16 C/D layout col=lane&15, row=(lane>>4)*4+j
  _Float16* dst = (EPI == 1) ? (C + (long)ks * M * N) : C;
#pragma unroll
  for (int mh = 0; mh < 2; ++mh)
#pragma unroll
  for (int m = 0; m < 4; ++m) {
    const long r0 = m0 + mh * 128 + wm * 64 + m * 16 + ls * 4;
#pragma unroll
    for (int nh = 0; nh < 2; ++nh)
#pragma unroll
    for (int n = 0; n < 2; ++n) {
      const long c = n0 + nh * 128 + wn * 32 + n * 16 + lh;
      const float bv = (EPI == 0) ? bias[c] : 0.f;
#pragma unroll
      for (int j = 0; j < 4; ++j)
        dst[(r0 + j) * N + c] = (_Float16)(acc[mh][nh][m][n][j] + bv);
    }
  }
#undef STAGE_A
#undef STAGE_B
#undef READ_A
#undef READ_B
#undef MM
#undef BAR
#undef VM6
#undef VM8
#undef PR1
#undef PR0
}

// ---------------- block-diagonal GEMM2 ----------------
__global__ __launch_bounds__(256) void k_gemm2(const _Float16* __restrict__ out1,
                                               const float* __restrict__ fc2w,
                                               const float* __restrict__ fc2b,
                                               _Float16* __restrict__ out2) {
  const int b0 = (blockIdx.x >> 4) * 64;
  const int p  = (blockIdx.x & 15) * 32 + (threadIdx.x & 31);
  const int bsub = threadIdx.x >> 5;
  f4 bb0 = *(const f4*)&fc2b[p * 16 + 0];
  f4 bb1 = *(const f4*)&fc2b[p * 16 + 4];
  f4 bb2 = *(const f4*)&fc2b[p * 16 + 8];
  f4 bb3 = *(const f4*)&fc2b[p * 16 + 12];
  for (int r = 0; r < 8; ++r) {
    const int b = b0 + r * 8 + bsub;
    h8 qv = *(const h8*)&out1[(long)b * NP1 + p * 8];
    f4 a0 = bb0, a1 = bb1, a2 = bb2, a3 = bb3;
#pragma unroll
    for (int i = 0; i < 8; ++i) {
      const float qi = (float)qv[i];
      const f4* wr = (const f4*)&fc2w[(long)(p * 8 + i) * NP2 + p * 16];
      a0 += qi * wr[0]; a1 += qi * wr[1]; a2 += qi * wr[2]; a3 += qi * wr[3];
    }
    h8 o0, o1;
#pragma unroll
    for (int u = 0; u < 4; ++u) {
      o0[u] = (_Float16)a0[u]; o0[4 + u] = (_Float16)a1[u];
      o1[u] = (_Float16)a2[u]; o1[4 + u] = (_Float16)a3[u];
    }
    h8* dstp = (h8*)&out2[(long)b * NP2 + p * 16];
    dstp[0] = o0; dstp[1] = o1;
  }
}

// ---------------- fused splitK-reduce + bias + relu + GEMM4 + sigmoid ----------------
__global__ __launch_bounds__(256) void k_logits(const _Float16* __restrict__ part,
                                                const float* __restrict__ b1,
                                                const float* __restrict__ w2,
                                                const float* __restrict__ b2,
                                                float* __restrict__ logits,
                                                float* __restrict__ hazards) {
  const int lane = threadIdx.x & 63;
  const int b = blockIdx.x * 4 + (threadIdx.x >> 6);
  const long off2 = (long)NB * NH;
  f4 acc = {0.f, 0.f, 0.f, 0.f};
  const _Float16* p0 = part + (long)b * NH;
  const _Float16* p1 = p0 + off2;
#pragma unroll
  for (int c4 = 0; c4 < 4; ++c4) {
    const int k0 = c4 * 512 + lane * 8;
    h8 a = *(const h8*)&p0[k0];
    h8 bb = *(const h8*)&p1[k0];
    f4 bva = *(const f4*)&b1[k0];
    f4 bvb = *(const f4*)&b1[k0 + 4];
#pragma unroll
    for (int u = 0; u < 8; ++u) {
      const float bias = (u < 4) ? bva[u] : bvb[u - 4];
      const float hv = fmaxf((float)a[u] + (float)bb[u] + bias, 0.f);
      acc += hv * *(const f4*)&w2[(long)(k0 + u) * 4];
    }
  }
#pragma unroll
  for (int off = 32; off > 0; off >>= 1) {
#pragma unroll
    for (int u = 0; u < 4; ++u) acc[u] += __shfl_xor(acc[u], off, 64);
  }
  if (lane == 0) {
    f4 lg = acc + *(const f4*)b2;
    ((f4*)logits)[b] = lg;
    f4 hz;
#pragma unroll
    for (int u = 0; u < 4; ++u) hz[u] = 1.f / (1.f + expf(-lg[u]));
    ((f4*)hazards)[b] = hz;
  }
}

// ---------------- cumprod along batch + first-occurrence argmax ----------------
__global__ __launch_bounds__(256) void k_final(const float* __restrict__ logits,
                                               const float* __restrict__ hazards,
                                               float* __restrict__ S,
                                               float* __restrict__ yhat) {
  const int c = blockIdx.x;
  const int t = threadIdx.x;
  __shared__ float pl[256];
  __shared__ float mv[256];
  __shared__ int   mi[256];
  float prod = 1.f;
  float best = -1e30f; int bi = 0;
  for (int i = 0; i < 16; ++i) {
    const int b = t * 16 + i;
    prod *= (1.f - hazards[b * 4 + c]);
    const float lg = logits[b * 4 + c];
    if (lg > best) { best = lg; bi = b; }
  }
  pl[t] = prod; mv[t] = best; mi[t] = bi;
  __syncthreads();
  for (int off = 1; off < 256; off <<= 1) {
    float cur  = pl[t];
    float prev = (t >= off) ? pl[t - off] : 1.f;
    __syncthreads();
    pl[t] = cur * prev;
    __syncthreads();
  }
  float s = (t == 0) ? 1.f : pl[t - 1];
  for (int i = 0; i < 16; ++i) {
    const int b = t * 16 + i;
    s *= (1.f - hazards[b * 4 + c]);
    S[b * 4 + c] = s;
  }
  for (int off = 128; off > 0; off >>= 1) {
    if (t < off) {
      float ov = mv[t + off]; int oi = mi[t + off];
      if (ov > mv[t] || (ov == mv[t] && oi < mi[t])) { mv[t] = ov; mi[t] = oi; }
    }
    __syncthreads();
  }
  if (t == 0) yhat[c] = (float)mi[0];
}

extern "C" void kernel_launch(void* const* d_in, const int* in_sizes, int n_in,
                              void* d_out, int out_size, void* d_ws, size_t ws_size,
                              hipStream_t stream) {
  (void)in_sizes; (void)n_in; (void)out_size; (void)ws_size;
  const float* x    = (const float*)d_in[0];
  const float* fc1w = (const float*)d_in[1];
  const float* fc1b = (const float*)d_in[2];
  const float* fc2w = (const float*)d_in[3];
  const float* fc2b = (const float*)d_in[4];
  const float* w1   = (const float*)d_in[5];
  const float* b1   = (const float*)d_in[6];
  const float* w2   = (const float*)d_in[7];
  const float* b2   = (const float*)d_in[8];
  const int*   comp = (const int*)d_in[9];

  char* ws = (char*)d_ws;
  const size_t MB = 1024ull * 1024ull;
  // region plan (peak 160MB):
  //   [0,32M)    xh     -> dead after GEMM1 -> w1Th
  //   [32M,64M)  w1mT   -> dead after GEMM1 -> part (fp16 2x16MB)
  //   [64M,96M)  out1h  -> dead after GEMM2 -> logits
  //   [96M,160M) out2h
  _Float16* xh     = (_Float16*)(ws + 0);
  _Float16* w1mT   = (_Float16*)(ws + 32 * MB);
  _Float16* out1h  = (_Float16*)(ws + 64 * MB);
  _Float16* out2h  = (_Float16*)(ws + 96 * MB);
  _Float16* w1Th   = (_Float16*)(ws + 0);
  _Float16* part   = (_Float16*)(ws + 32 * MB);
  float*    logits = (float*)(ws + 64 * MB);
  float*    outF   = (float*)d_out;

  hipFuncSetAttribute(reinterpret_cast<const void*>(k_gemm8<0>),
                      hipFuncAttributeMaxDynamicSharedMemorySize, 131072);
  hipFuncSetAttribute(reinterpret_cast<const void*>(k_gemm8<1>),
                      hipFuncAttributeMaxDynamicSharedMemorySize, 131072);

  // 1) pack x -> fp16
  k_pack_f16<<<(NB * NIN / 4) / 256, 256, 0, stream>>>(x, xh, NB * NIN / 4);
  // 2) pack (fc1_w * mask1)^T -> fp16 [P1][IN]
  k_packT<true><<<dim3(NP1 / 64, NIN / 64), 256, 0, stream>>>(fc1w, comp, w1mT, NIN, NP1);
  // 3) GEMM1: out1 = x @ fc1w_masked + fc1_b
  k_gemm8<0><<<(NB / 256) * (NP1 / 256), 512, 131072, stream>>>(
      xh, w1mT, fc1b, out1h, NB, NP1, NIN, NP1 / 256, 1);
  // 4) block-diagonal GEMM2 -> out2 fp16
  k_gemm2<<<(NB / 64) * (NNP / 32), 256, 0, stream>>>(out1h, fc2w, fc2b, out2h);
  // 5) pack w1^T -> fp16 [H][P2] (overlays dead xh)
  k_packT<false><<<dim3(NH / 64, NP2 / 64), 256, 0, stream>>>(w1, nullptr, w1Th, NP2, NH);
  // 6) GEMM3 split-K=2: fp16 partials = out2 @ w1 (overlays dead w1mT)
  k_gemm8<1><<<(NB / 256) * (NH / 256) * 2, 512, 131072, stream>>>(
      out2h, w1Th, nullptr, part, NB, NH, NP2, NH / 256, 2);
  // 7) fused: h = relu(p0+p1+b1); logits = h@w2+b2; hazards = sigmoid
  k_logits<<<NB / 4, 256, 0, stream>>>(part, b1, w2, b2, logits, outF);
  // 8) S and Y_hat
  k_final<<<4, 256, 0, stream>>>(logits, outF, outF + NB * 4, outF + 2 * NB * 4);
}

// Round 9
// 336.373 us; speedup vs baseline: 1.1528x; 1.0013x over previous
//
#include <hip/hip_runtime.h>
#include <cmath>

typedef _Float16 h8  __attribute__((ext_vector_type(8)));
typedef _Float16 h4v __attribute__((ext_vector_type(4)));
typedef float    f4  __attribute__((ext_vector_type(4)));

#define NB  4096
#define NIN 4096
#define NNP 512
#define NP1 4096
#define NP2 8192
#define NH  2048

__device__ __forceinline__ void g2l(const void* g, void* l) {
  __builtin_amdgcn_global_load_lds((const __attribute__((address_space(1))) void*)g,
                                   (__attribute__((address_space(3))) void*)l, 16, 0, 0);
}

// ---------------- pack f32 -> f16 (vectorized) ----------------
__global__ __launch_bounds__(256) void k_pack_f16(const float* __restrict__ in,
                                                  _Float16* __restrict__ out, int n4) {
  int i = blockIdx.x * 256 + threadIdx.x;
  if (i >= n4) return;
  f4 v = ((const f4*)in)[i];
  h4v o;
  o[0] = (_Float16)v[0]; o[1] = (_Float16)v[1];
  o[2] = (_Float16)v[2]; o[3] = (_Float16)v[3];
  ((h4v*)out)[i] = o;
}

// ---------------- transpose pack: out[n][k] = in[k][n] * optional mask ----------------
template<bool MASK>
__global__ __launch_bounds__(256) void k_packT(const float* __restrict__ in,
                                               const int* __restrict__ comp,
                                               _Float16* __restrict__ out, int K, int N) {
  __shared__ float tile[64][65];
  const int n0 = blockIdx.x * 64, k0 = blockIdx.y * 64;
  const int tx = threadIdx.x & 63, ty = threadIdx.x >> 6;
#pragma unroll
  for (int r = 0; r < 16; ++r) {
    int kk = r * 4 + ty;
    float v = in[(long)(k0 + kk) * N + n0 + tx];
    if (MASK) v *= (float)comp[(long)(k0 + kk) * NNP + ((n0 + tx) >> 3)];
    tile[kk][tx] = v;
  }
  __syncthreads();
#pragma unroll
  for (int r = 0; r < 16; ++r) {
    int nn = r * 4 + ty;
    out[(long)(n0 + nn) * K + k0 + tx] = (_Float16)tile[tx][nn];
  }
}

// ---------------- 256x256 fp16 GEMM, 16x16x32 frags, read-ahead pipelined 8-phase ----------------
// C = A[M,K] * BT[N,K]^T. EPI=0: C = acc + bias (fp16). EPI=1: fp16 split-K partial at ks*M*N.
// 8 waves (2m x 4n). A row = mh*128 + wm*64 + m*16 + lh ; B row = nh*128 + wn*32 + n*16 + lh.
// LDS 128KB: 2buf x {A half0,half1 ; B half0,half1}, each half [128 rows][128B] fp16.
// Zero-conflict read col (verified R6): (kq*64 + ls*16) ^ ((lh&7)<<4); staging = linear LDS
// dest + pre-swizzled global source.
// Pipelining: each phase's ds_reads load the NEXT phase's fragments into alternate register
// sets (afA/afB, bfA/bfB; B parity swaps per tile) -> MFMA never waits on LDS latency.
// Stages for tile t+2 spread P1..P4 of tile t; one vmcnt(6) per K-tile (ledger: 14 out, retires
// exactly the next tile's 8 stages). Plain ds_reads: compiler emits counted lgkm waits.
template<int EPI>
__global__ __launch_bounds__(512, 1) void k_gemm8(
    const _Float16* __restrict__ A, const _Float16* __restrict__ BT,
    const float* __restrict__ bias, _Float16* __restrict__ C,
    int M, int N, int K, int nbn, int ksplit) {
  extern __shared__ char smem[];
  // bijective XCD swizzle
  const int nwg = gridDim.x;
  const int q = nwg >> 3, r = nwg & 7;
  const int xcd = blockIdx.x & 7, idx = blockIdx.x >> 3;
  const int wg = (xcd < r ? xcd * (q + 1) : r * (q + 1) + (xcd - r) * q) + idx;
  const int tpk = nwg / ksplit;
  const int ks = wg / tpk;
  const int rem = wg - ks * tpk;
  const int bm = rem / nbn, bn = rem % nbn;
  const long m0 = (long)bm << 8, n0 = (long)bn << 8;
  const int Ks = K / ksplit;
  const int NT = Ks >> 6;              // BK=64, NT even (K multiples of 128)

  const int tid = threadIdx.x;
  const int lane = tid & 63, w = tid >> 6;
  const int wm = w >> 2, wn = w & 3;
  const int lh = lane & 15, ls = lane >> 4;
  const int swz = (lh & 7) << 4;
  const int c0 = (ls * 16) ^ swz;
  const int c1 = (64 + ls * 16) ^ swz;
  const int arow = (wm * 64 + lh) * 128;           // + mh*16384 + m_*2048
  const int brow = 32768 + (wn * 32 + lh) * 128;   // + nh*16384 + n_*2048

  const long sKb = (long)K * 2;
  const int scb = (((tid & 7) ^ ((tid >> 3) & 7)) << 4);
  const char* Ag = (const char*)A + (m0 + (tid >> 3)) * sKb + (long)ks * Ks * 2 + scb;
  const char* Bg = (const char*)BT + (n0 + (tid >> 3)) * sKb + (long)ks * Ks * 2 + scb;
  const long h64 = 64 * sKb, h128 = 128 * sKb;
  const int lw = w << 10;

#define STAGE_A(buf, hh, kb) do { \
    const char* s_ = Ag + (hh) * h128 + (kb); \
    char* d_ = smem + (buf) * 65536 + (hh) * 16384 + lw; \
    g2l(s_, d_); g2l(s_ + h64, d_ + 8192); } while (0)
#define STAGE_B(buf, hh, kb) do { \
    const char* s_ = Bg + (hh) * h128 + (kb); \
    char* d_ = smem + (buf) * 65536 + 32768 + (hh) * 16384 + lw; \
    g2l(s_, d_); g2l(s_ + h64, d_ + 8192); } while (0)
#define READ_A(dst, buf, mh) do { \
    _Pragma("unroll") for (int m_ = 0; m_ < 4; ++m_) { \
      dst[m_][0] = *(const h8*)(smem + (buf) * 65536 + (mh) * 16384 + arow + m_ * 2048 + c0); \
      dst[m_][1] = *(const h8*)(smem + (buf) * 65536 + (mh) * 16384 + arow + m_ * 2048 + c1); } } while (0)
#define READ_B(dst, buf, nh) do { \
    _Pragma("unroll") for (int n_ = 0; n_ < 2; ++n_) { \
      dst[n_][0] = *(const h8*)(smem + (buf) * 65536 + (nh) * 16384 + brow + n_ * 2048 + c0); \
      dst[n_][1] = *(const h8*)(smem + (buf) * 65536 + (nh) * 16384 + brow + n_ * 2048 + c1); } } while (0)
#define MM(mh, nh, aset, bset) do { \
    _Pragma("unroll") for (int kq_ = 0; kq_ < 2; ++kq_) \
    _Pragma("unroll") for (int m_ = 0; m_ < 4; ++m_) \
    _Pragma("unroll") for (int n_ = 0; n_ < 2; ++n_) \
      acc[mh][nh][m_][n_] = __builtin_amdgcn_mfma_f32_16x16x32_f16(aset[m_][kq_], bset[n_][kq_], acc[mh][nh][m_][n_], 0, 0, 0); } while (0)
#define BAR() asm volatile("s_barrier" ::: "memory")
#define VM6() asm volatile("s_waitcnt vmcnt(6)" ::: "memory")
#define VM8() asm volatile("s_waitcnt vmcnt(8)" ::: "memory")
#define PR1() __builtin_amdgcn_s_setprio(1)
#define PR0() __builtin_amdgcn_s_setprio(0)

  f4 acc[2][2][4][2] = {};   // [mh][nh][m][n]
  h8 afA[4][2], afB[4][2];   // A half0 / half1 fragment sets
  h8 bfA[2][2], bfB[2][2];   // B sets: even tiles B0->bfA,B1->bfB; odd tiles swapped

  auto kc = [&](int t) -> long { return (long)(t < NT ? t : NT - 1) << 7; };

  // prologue: stage tile0->buf0 (8 g2l), tile1->buf1 (8 g2l); retire tile0; preload A0,B0(t0)
  STAGE_A(0, 0, kc(0)); STAGE_B(0, 0, kc(0)); STAGE_B(0, 1, kc(0)); STAGE_A(0, 1, kc(0));
  STAGE_A(1, 0, kc(1)); STAGE_B(1, 0, kc(1)); STAGE_B(1, 1, kc(1)); STAGE_A(1, 1, kc(1));
  VM8();
  BAR();
  READ_A(afA, 0, 0);
  READ_B(bfA, 0, 0);

  for (int t2 = 0; t2 < NT; t2 += 2) {
    // ================= even tile t2 (buf0) =================
    // P1: MFMA(A0,B0); read B1(t2) ahead; stage A0(t2+2)
    BAR();
    READ_B(bfB, 0, 1);
    STAGE_A(0, 0, kc(t2 + 2));
    PR1(); MM(0, 0, afA, bfA); PR0();
    // P2: MFMA(A0,B1); read A1(t2) ahead; stage B1(t2+2)
    BAR();
    READ_A(afB, 0, 1);
    STAGE_B(0, 1, kc(t2 + 2));
    PR1(); MM(0, 1, afA, bfB); PR0();
    // P3: MFMA(A1,B1); gate tile t2+1 (vmcnt ledger = 14 -> retire its 8); read A0(t2+1)
    BAR();
    STAGE_A(0, 1, kc(t2 + 2));
    VM6();
    READ_A(afA, 1, 0);
    PR1(); MM(1, 1, afB, bfB); PR0();
    // P4: MFMA(A1,B0); read B0(t2+1)->bfB (odd parity); stage B0(t2+2)
    BAR();
    READ_B(bfB, 1, 0);
    STAGE_B(0, 0, kc(t2 + 2));
    PR1(); MM(1, 0, afB, bfA); PR0();
    // ================= odd tile t2+1 (buf1) =================
    // P5: MFMA(A0,B0=bfB); read B1(t2+1)->bfA; stage A0(t2+3)
    BAR();
    READ_B(bfA, 1, 1);
    STAGE_A(1, 0, kc(t2 + 3));
    PR1(); MM(0, 0, afA, bfB); PR0();
    // P6: MFMA(A0,B1=bfA); read A1(t2+1); stage B1(t2+3)
    BAR();
    READ_A(afB, 1, 1);
    STAGE_B(1, 1, kc(t2 + 3));
    PR1(); MM(0, 1, afA, bfA); PR0();
    // P7: MFMA(A1,B1=bfA); gate tile t2+2 (retire P1..P4 stages); read A0(t2+2)
    BAR();
    STAGE_A(1, 1, kc(t2 + 3));
    VM6();
    READ_A(afA, 0, 0);
    PR1(); MM(1, 1, afB, bfA); PR0();
    // P8: MFMA(A1,B0=bfB); read B0(t2+2)->bfA (even parity); stage B0(t2+3)
    BAR();
    READ_B(bfA, 0, 0);
    STAGE_B(1, 0, kc(t2 + 3));
    PR1(); MM(1, 0, afB, bfB); PR0();
  }

  // epilogue: 16x16 C/D layout col=lane&15, row=(lane>>4)*4+j
  _Float16* dst = (EPI == 1) ? (C + (long)ks * M * N) : C;
#pragma unroll
  for (int mh = 0; mh < 2; ++mh)
#pragma unroll
  for (int m = 0; m < 4; ++m) {
    const long r0 = m0 + mh * 128 + wm * 64 + m * 16 + ls * 4;
#pragma unroll
    for (int nh = 0; nh < 2; ++nh)
#pragma unroll
    for (int n = 0; n < 2; ++n) {
      const long c = n0 + nh * 128 + wn * 32 + n * 16 + lh;
      const float bv = (EPI == 0) ? bias[c] : 0.f;
#pragma unroll
      for (int j = 0; j < 4; ++j)
        dst[(r0 + j) * N + c] = (_Float16)(acc[mh][nh][m][n][j] + bv);
    }
  }
#undef STAGE_A
#undef STAGE_B
#undef READ_A
#undef READ_B
#undef MM
#undef BAR
#undef VM6
#undef VM8
#undef PR1
#undef PR0
}

// ---------------- block-diagonal GEMM2 ----------------
__global__ __launch_bounds__(256) void k_gemm2(const _Float16* __restrict__ out1,
                                               const float* __restrict__ fc2w,
                                               const float* __restrict__ fc2b,
                                               _Float16* __restrict__ out2) {
  const int b0 = (blockIdx.x >> 4) * 64;
  const int p  = (blockIdx.x & 15) * 32 + (threadIdx.x & 31);
  const int bsub = threadIdx.x >> 5;
  f4 bb0 = *(const f4*)&fc2b[p * 16 + 0];
  f4 bb1 = *(const f4*)&fc2b[p * 16 + 4];
  f4 bb2 = *(const f4*)&fc2b[p * 16 + 8];
  f4 bb3 = *(const f4*)&fc2b[p * 16 + 12];
  for (int r = 0; r < 8; ++r) {
    const int b = b0 + r * 8 + bsub;
    h8 qv = *(const h8*)&out1[(long)b * NP1 + p * 8];
    f4 a0 = bb0, a1 = bb1, a2 = bb2, a3 = bb3;
#pragma unroll
    for (int i = 0; i < 8; ++i) {
      const float qi = (float)qv[i];
      const f4* wr = (const f4*)&fc2w[(long)(p * 8 + i) * NP2 + p * 16];
      a0 += qi * wr[0]; a1 += qi * wr[1]; a2 += qi * wr[2]; a3 += qi * wr[3];
    }
    h8 o0, o1;
#pragma unroll
    for (int u = 0; u < 4; ++u) {
      o0[u] = (_Float16)a0[u]; o0[4 + u] = (_Float16)a1[u];
      o1[u] = (_Float16)a2[u]; o1[4 + u] = (_Float16)a3[u];
    }
    h8* dstp = (h8*)&out2[(long)b * NP2 + p * 16];
    dstp[0] = o0; dstp[1] = o1;
  }
}

// ---------------- fused splitK-reduce + bias + relu + GEMM4 + sigmoid ----------------
__global__ __launch_bounds__(256) void k_logits(const _Float16* __restrict__ part,
                                                const float* __restrict__ b1,
                                                const float* __restrict__ w2,
                                                const float* __restrict__ b2,
                                                float* __restrict__ logits,
                                                float* __restrict__ hazards) {
  const int lane = threadIdx.x & 63;
  const int b = blockIdx.x * 4 + (threadIdx.x >> 6);
  const long off2 = (long)NB * NH;
  f4 acc = {0.f, 0.f, 0.f, 0.f};
  const _Float16* p0 = part + (long)b * NH;
  const _Float16* p1 = p0 + off2;
#pragma unroll
  for (int c4 = 0; c4 < 4; ++c4) {
    const int k0 = c4 * 512 + lane * 8;
    h8 a = *(const h8*)&p0[k0];
    h8 bb = *(const h8*)&p1[k0];
    f4 bva = *(const f4*)&b1[k0];
    f4 bvb = *(const f4*)&b1[k0 + 4];
#pragma unroll
    for (int u = 0; u < 8; ++u) {
      const float bias = (u < 4) ? bva[u] : bvb[u - 4];
      const float hv = fmaxf((float)a[u] + (float)bb[u] + bias, 0.f);
      acc += hv * *(const f4*)&w2[(long)(k0 + u) * 4];
    }
  }
#pragma unroll
  for (int off = 32; off > 0; off >>= 1) {
#pragma unroll
    for (int u = 0; u < 4; ++u) acc[u] += __shfl_xor(acc[u], off, 64);
  }
  if (lane == 0) {
    f4 lg = acc + *(const f4*)b2;
    ((f4*)logits)[b] = lg;
    f4 hz;
#pragma unroll
    for (int u = 0; u < 4; ++u) hz[u] = 1.f / (1.f + expf(-lg[u]));
    ((f4*)hazards)[b] = hz;
  }
}

// ---------------- cumprod along batch + first-occurrence argmax ----------------
__global__ __launch_bounds__(256) void k_final(const float* __restrict__ logits,
                                               const float* __restrict__ hazards,
                                               float* __restrict__ S,
                                               float* __restrict__ yhat) {
  const int c = blockIdx.x;
  const int t = threadIdx.x;
  __shared__ float pl[256];
  __shared__ float mv[256];
  __shared__ int   mi[256];
  float prod = 1.f;
  float best = -1e30f; int bi = 0;
  for (int i = 0; i < 16; ++i) {
    const int b = t * 16 + i;
    prod *= (1.f - hazards[b * 4 + c]);
    const float lg = logits[b * 4 + c];
    if (lg > best) { best = lg; bi = b; }
  }
  pl[t] = prod; mv[t] = best; mi[t] = bi;
  __syncthreads();
  for (int off = 1; off < 256; off <<= 1) {
    float cur  = pl[t];
    float prev = (t >= off) ? pl[t - off] : 1.f;
    __syncthreads();
    pl[t] = cur * prev;
    __syncthreads();
  }
  float s = (t == 0) ? 1.f : pl[t - 1];
  for (int i = 0; i < 16; ++i) {
    const int b = t * 16 + i;
    s *= (1.f - hazards[b * 4 + c]);
    S[b * 4 + c] = s;
  }
  for (int off = 128; off > 0; off >>= 1) {
    if (t < off) {
      float ov = mv[t + off]; int oi = mi[t + off];
      if (ov > mv[t] || (ov == mv[t] && oi < mi[t])) { mv[t] = ov; mi[t] = oi; }
    }
    __syncthreads();
  }
  if (t == 0) yhat[c] = (float)mi[0];
}

extern "C" void kernel_launch(void* const* d_in, const int* in_sizes, int n_in,
                              void* d_out, int out_size, void* d_ws, size_t ws_size,
                              hipStream_t stream) {
  (void)in_sizes; (void)n_in; (void)out_size; (void)ws_size;
  const float* x    = (const float*)d_in[0];
  const float* fc1w = (const float*)d_in[1];
  const float* fc1b = (const float*)d_in[2];
  const float* fc2w = (const float*)d_in[3];
  const float* fc2b = (const float*)d_in[4];
  const float* w1   = (const float*)d_in[5];
  const float* b1   = (const float*)d_in[6];
  const float* w2   = (const float*)d_in[7];
  const float* b2   = (const float*)d_in[8];
  const int*   comp = (const int*)d_in[9];

  char* ws = (char*)d_ws;
  const size_t MB = 1024ull * 1024ull;
  // region plan (peak 160MB):
  //   [0,32M)    xh     -> dead after GEMM1 -> w1Th
  //   [32M,64M)  w1mT   -> dead after GEMM1 -> part (fp16 2x16MB)
  //   [64M,96M)  out1h  -> dead after GEMM2 -> logits
  //   [96M,160M) out2h
  _Float16* xh     = (_Float16*)(ws + 0);
  _Float16* w1mT   = (_Float16*)(ws + 32 * MB);
  _Float16* out1h  = (_Float16*)(ws + 64 * MB);
  _Float16* out2h  = (_Float16*)(ws + 96 * MB);
  _Float16* w1Th   = (_Float16*)(ws + 0);
  _Float16* part   = (_Float16*)(ws + 32 * MB);
  float*    logits = (float*)(ws + 64 * MB);
  float*    outF   = (float*)d_out;

  hipFuncSetAttribute(reinterpret_cast<const void*>(k_gemm8<0>),
                      hipFuncAttributeMaxDynamicSharedMemorySize, 131072);
  hipFuncSetAttribute(reinterpret_cast<const void*>(k_gemm8<1>),
                      hipFuncAttributeMaxDynamicSharedMemorySize, 131072);

  // 1) pack x -> fp16
  k_pack_f16<<<(NB * NIN / 4) / 256, 256, 0, stream>>>(x, xh, NB * NIN / 4);
  // 2) pack (fc1_w * mask1)^T -> fp16 [P1][IN]
  k_packT<true><<<dim3(NP1 / 64, NIN / 64), 256, 0, stream>>>(fc1w, comp, w1mT, NIN, NP1);
  // 3) GEMM1: out1 = x @ fc1w_masked + fc1_b
  k_gemm8<0><<<(NB / 256) * (NP1 / 256), 512, 131072, stream>>>(
      xh, w1mT, fc1b, out1h, NB, NP1, NIN, NP1 / 256, 1);
  // 4) block-diagonal GEMM2 -> out2 fp16
  k_gemm2<<<(NB / 64) * (NNP / 32), 256, 0, stream>>>(out1h, fc2w, fc2b, out2h);
  // 5) pack w1^T -> fp16 [H][P2] (overlays dead xh)
  k_packT<false><<<dim3(NH / 64, NP2 / 64), 256, 0, stream>>>(w1, nullptr, w1Th, NP2, NH);
  // 6) GEMM3 split-K=2: fp16 partials = out2 @ w1 (overlays dead w1mT)
  k_gemm8<1><<<(NB / 256) * (NH / 256) * 2, 512, 131072, stream>>>(
      out2h, w1Th, nullptr, part, NB, NH, NP2, NH / 256, 2);
  // 7) fused: h = relu(p0+p1+b1); logits = h@w2+b2; hazards = sigmoid
  k_logits<<<NB / 4, 256, 0, stream>>>(part, b1, w2, b2, logits, outF);
  // 8) S and Y_hat
  k_final<<<4, 256, 0, stream>>>(logits, outF, outF + NB * 4, outF + 2 * NB * 4);
}